// Round 16
// baseline (653.252 us; speedup 1.0000x reference)
//
#include <hip/hip_runtime.h>
#include <hip/hip_fp16.h>

static constexpr int B  = 4;
static constexpr int H0 = 256, W0 = 448, HW0 = H0 * W0;   // full
static constexpr int H1 = 128, W1 = 224, HW1 = H1 * W1;   // half
static constexpr int H2 = 64,  W2 = 112, HW2 = H2 * W2;   // quarter

typedef _Float16 half8_t __attribute__((ext_vector_type(8)));
typedef _Float16 half4_t __attribute__((ext_vector_type(4)));
typedef _Float16 half2v  __attribute__((ext_vector_type(2)));
typedef float floatx4 __attribute__((ext_vector_type(4)));

static constexpr int NC_F = (W0 + 1) * (H0 + 1);
static constexpr int NC_H = (W1 + 1) * (H1 + 1);
static constexpr int NC_Q = (W2 + 1) * (H2 + 1);

static constexpr int RS_F = 20;
static constexpr int RS_H = 36;
static constexpr int RS_Q = 52;

static constexpr int SZ_F = 2 * B * NC_F;
static constexpr int SZ_H = 2 * B * NC_H;
static constexpr int SZ_Q = 2 * B * NC_Q;
static constexpr int CNT_TOTAL = SZ_F + SZ_H + SZ_Q;

static constexpr int CHUNK = 16384;
static constexpr int NCH_F = (SZ_F + CHUNK - 1) / CHUNK;
static constexpr int NCH_H = (SZ_H + CHUNK - 1) / CHUNK;
static constexpr int NCH_Q = (SZ_Q + CHUNK - 1) / CHUNK;
static constexpr int NCHUNKS = NCH_F + NCH_H + NCH_Q;     // 76

// ---------------- workspace layout (floats) ----------------
static constexpr size_t OFF_MEAN   = 0;
static constexpr size_t OFF_CNT    = 256;
static constexpr size_t ZERO_FLOATS = OFF_CNT + CNT_TOTAL;   // divisible by 4
static constexpr size_t OFF_BUFA   = ZERO_FLOATS;
static constexpr size_t OFF_BUFB   = OFF_BUFA + (size_t)4 * 32 * HW0;
static constexpr size_t OFF_FLOW   = OFF_BUFB + (size_t)4 * 32 * HW0;
static constexpr size_t OFF_FLH    = OFF_FLOW + (size_t)2 * B * 2 * HW0;
static constexpr size_t OFF_FLQ    = OFF_FLH + (size_t)2 * B * 2 * HW1;
static constexpr size_t OFF_WT2 = OFF_FLQ + (size_t)2 * B * 2 * HW2;
static constexpr size_t OFF_WT3 = OFF_WT2 + 4608;
static constexpr size_t OFF_WT4 = OFF_WT3 + 9216;
static constexpr size_t OFF_WT5 = OFF_WT4 + 18432;
static constexpr size_t OFF_WT6 = OFF_WT5 + 27648;
static constexpr size_t OFF_CS   = OFF_WT6 + 41472;
static constexpr size_t OFF_CURS = OFF_CS + (size_t)2 * CNT_TOTAL;
static constexpr size_t OFF_TPRE = OFF_CURS + CNT_TOTAL;
static constexpr size_t OFF_PSUM = OFF_TPRE + (size_t)NCHUNKS * 256;
static constexpr size_t OFF_RECS = OFF_PSUM + 128;
static constexpr size_t WS_FLOATS = OFF_RECS + (size_t)2 * B * HW0 * RS_F;

// ---------------- output layout (floats) ----------------
static constexpr size_t O_IMG = 0;
static constexpr size_t O_F1  = O_IMG + (size_t)B * 6 * HW0;
static constexpr size_t O_F2  = O_F1  + (size_t)B * 64 * HW0;
static constexpr size_t O_F3  = O_F2  + (size_t)B * 128 * HW1;
static constexpr size_t O_SIG = O_F3  + (size_t)B * 192 * HW2;

// sub-grid block counts (all multiples of 8 -> bijective XCD swizzle)
static constexpr int NB_IF = 2 * B * HW0 / 256;   // 3584
static constexpr int NB_MEAN = 32 * B;            // 128
static constexpr int NB_WT = (202752 + 255) / 256;// 792
static constexpr int NB_DH = 2 * B * HW1 / 256;   // 896
static constexpr int NB_DQ = 2 * B * HW2 / 256;   // 224
static constexpr int NB_C1 = 448 * 8;             // 3584
static constexpr int NB_C2 = 224 * 8;             // 1792
static constexpr int NB_PF = (HW0 / 256) * B * 2; // 3584
static constexpr int NB_C3 = 112 * 2 * 8;         // 1792
static constexpr int NB_GF = (HW0 / 256) * B * 2 * 2; // 7168 (2 ch-chunks)
static constexpr int NB_C4 = 56 * 2 * 8;          // 896
static constexpr int NB_PH = (HW1 / 256) * B * 2; // 896
static constexpr int NB_C5 = 28 * 3 * 8;          // 672
static constexpr int NB_GH = (HW1 / 256) * B * 2 * 4; // 3584 (16-ch chunks)
static constexpr int NB_C6 = 28 * 3 * 8;          // 672

__device__ inline unsigned f2h(float lo, float hi) {
  __half2 h = __floats2half2_rn(lo, hi);
  return *reinterpret_cast<unsigned*>(&h);
}

__device__ inline void chunk_map(int b, int& off, int& sz, int& ci) {
  if (b < NCH_F)              { off = 0;           sz = SZ_F; ci = b; }
  else if (b < NCH_F + NCH_H) { off = SZ_F;        sz = SZ_H; ci = b - NCH_F; }
  else                        { off = SZ_F + SZ_H; sz = SZ_Q; ci = b - NCH_F - NCH_H; }
}

// ---------------- fast zero ----------------
__global__ __launch_bounds__(256) void k_zero(floatx4* __restrict__ p, int n4) {
  floatx4 z = {};
  for (int i = blockIdx.x * 256 + threadIdx.x; i < n4; i += gridDim.x * 256)
    p[i] = z;
}

// ================= device bodies =================

__device__ __forceinline__ void d_mean(const float* __restrict__ img0,
                                       const float* __restrict__ img1,
                                       float* __restrict__ msum, int s) {
  const int perImg = 3 * HW0;
  int bx = s & 31, b = s >> 5;
  float acc = 0.f;
  int tot = 2 * perImg;
  for (int i = bx * 256 + threadIdx.x; i < tot; i += 32 * 256) {
    acc += (i < perImg) ? img0[(size_t)b * perImg + i] : img1[(size_t)b * perImg + (i - perImg)];
  }
#pragma unroll
  for (int o = 32; o > 0; o >>= 1) acc += __shfl_down(acc, o);
  __shared__ float red[4];
  int lane = threadIdx.x & 63, wid = threadIdx.x >> 6;
  if (lane == 0) red[wid] = acc;
  __syncthreads();
  if (threadIdx.x == 0) atomicAdd(&msum[b], red[0] + red[1] + red[2] + red[3]);
}

__device__ __forceinline__ void d_interflow2(
    const float* __restrict__ f01, const float* __restrict__ s01,
    const float* __restrict__ f10, const float* __restrict__ s10,
    float* __restrict__ outBase, unsigned* __restrict__ cntF, int s) {
  constexpr int NCX = W0 + 1;
  int i = s * 256 + (int)threadIdx.x;
  if (i >= 2 * B * HW0) return;
  int nb = i / HW0;
  int px = i - nb * HW0;
  int dir = nb >> 2, b = nb & 3;
  const float* flo = dir ? f10 : f01;
  const float* sigma = dir ? s10 : s01;
  float fx = flo[((size_t)(b * 2 + 0)) * HW0 + px];
  float fy = flo[((size_t)(b * 2 + 1)) * HW0 + px];
  float sg = sigma[(size_t)b * HW0 + px];
  float ftx, fty;
  if (fabsf(sg) < 0.01f) {
    ftx = 0.5f * fx; fty = 0.5f * fy;
  } else {
    float g = (1.f - sqrtf(fmaxf(0.f, 1.f - sg * sg))) / (2.f * sg);
    ftx = 0.5f * fx - g * fy;
    fty = 0.5f * fy + g * fx;
  }
  outBase[((size_t)(nb * 2 + 0)) * HW0 + px] = ftx;
  outBase[((size_t)(nb * 2 + 1)) * HW0 + px] = fty;
  int sw = px % W0, sh = px / W0;
  float tx = (float)sw + ftx, ty = (float)sh + fty;
  int x0 = (int)floorf(tx), y0 = (int)floorf(ty);
  if (x0 >= -1 && x0 <= W0 - 1 && y0 >= -1 && y0 <= H0 - 1)
    atomicAdd(&cntF[nb * NC_F + (y0 + 1) * NCX + (x0 + 1)], 1u);
}

template <int F, int Hd, int Wd>
__device__ __forceinline__ void d_downflow2(
    const float* __restrict__ in, float* __restrict__ out,
    unsigned* __restrict__ cnt, int s) {
  constexpr int HWd = Hd * Wd;
  constexpr int NCX = Wd + 1;
  constexpr int NC  = (Wd + 1) * (Hd + 1);
  int i = s * 256 + (int)threadIdx.x;
  if (i >= 2 * B * HWd) return;
  int nb = i / HWd;
  int px = i - nb * HWd;
  int ow = px % Wd, oh = px / Wd;
  float cy = (oh + 0.5f) * F - 0.5f;
  float cx = (ow + 0.5f) * F - 0.5f;
  int ylo = (int)floorf(cy) - F + 1;
  int xlo = (int)floorf(cx) - F + 1;
  const float* ipx = in + ((size_t)(nb * 2 + 0)) * HW0;
  const float* ipy = in + ((size_t)(nb * 2 + 1)) * HW0;
  float ax = 0.f, ay = 0.f, wn = 0.f;
  for (int jy = 0; jy < 2 * F; jy++) {
    int y = ylo + jy;
    if ((unsigned)y >= (unsigned)H0) continue;
    float wy = 1.f - fabsf((float)y - cy) / (float)F;
    for (int jx = 0; jx < 2 * F; jx++) {
      int x = xlo + jx;
      if ((unsigned)x >= (unsigned)W0) continue;
      float wx = 1.f - fabsf((float)x - cx) / (float)F;
      float ww = wy * wx;
      ax += ww * ipx[(size_t)y * W0 + x];
      ay += ww * ipy[(size_t)y * W0 + x];
      wn += ww;
    }
  }
  float sc = 1.f / (wn * (float)F);
  float fx = ax * sc, fy = ay * sc;
  out[((size_t)(nb * 2 + 0)) * HWd + px] = fx;
  out[((size_t)(nb * 2 + 1)) * HWd + px] = fy;
  float tx = (float)ow + fx, ty = (float)oh + fy;
  int x0 = (int)floorf(tx), y0 = (int)floorf(ty);
  if (x0 >= -1 && x0 <= Wd - 1 && y0 >= -1 && y0 <= Hd - 1)
    atomicAdd(&cnt[nb * NC + (y0 + 1) * NCX + (x0 + 1)], 1u);
}

__device__ __forceinline__ void d_wtrans(
    const float* __restrict__ w2, const float* __restrict__ w3,
    const float* __restrict__ w4, const float* __restrict__ w5,
    const float* __restrict__ w6,
    _Float16* __restrict__ o2, _Float16* __restrict__ o3,
    _Float16* __restrict__ o4, _Float16* __restrict__ o5,
    _Float16* __restrict__ o6, int s) {
  int i = s * 256 + (int)threadIdx.x;
  const float* w; _Float16* o; int COUT, CIN, base;
  if      (i <   9216) { w = w2; o = o2; COUT = 32; CIN = 32; base = 0; }
  else if (i <  27648) { w = w3; o = o3; COUT = 64; CIN = 32; base = 9216; }
  else if (i <  64512) { w = w4; o = o4; COUT = 64; CIN = 64; base = 27648; }
  else if (i < 119808) { w = w5; o = o5; COUT = 96; CIN = 64; base = 64512; }
  else if (i < 202752) { w = w6; o = o6; COUT = 96; CIN = 96; base = 119808; }
  else return;
  int j = i - base;
  int q = j % 9;
  int rest = j / 9;
  int ci = rest % CIN;
  int co = rest / CIN;
  o[((size_t)q * COUT + co) * CIN + ci] = (_Float16)w[j];
}

__device__ __forceinline__ void d_conv1(
    const float* __restrict__ img0, const float* __restrict__ img1,
    const float* __restrict__ msum, float invCnt,
    const float* __restrict__ wgt, const float* __restrict__ bias,
    const float* __restrict__ alpha, _Float16* __restrict__ outp, int s) {
  __shared__ float wsm[32 * 27];
  __shared__ float bsm[32];
  int bx = s % 448, n = s / 448;
  for (int i = threadIdx.x; i < 32 * 27; i += 256) wsm[i] = wgt[i];
  if (threadIdx.x < 32) bsm[threadIdx.x] = bias[threadIdx.x];
  __syncthreads();
  int b = n & 3;
  const float* ip = (n < 4 ? img0 : img1) + (size_t)b * 3 * HW0;
  float m = msum[b] * invCnt;
  int tx = bx % 7, ty = bx / 7;
  int ow = tx * 64 + (threadIdx.x & 63);
  int oh = ty * 4 + (threadIdx.x >> 6);
  float xv[27];
#pragma unroll
  for (int ci = 0; ci < 3; ci++) {
    const float* iq = ip + (size_t)ci * HW0;
#pragma unroll
    for (int ky = 0; ky < 3; ky++) {
      int y = oh - 1 + ky;
      bool yv = (unsigned)y < (unsigned)H0;
      const float* row = iq + (size_t)y * W0;
#pragma unroll
      for (int kx = 0; kx < 3; kx++) {
        int x = ow - 1 + kx;
        xv[ci * 9 + ky * 3 + kx] = (yv && (unsigned)x < (unsigned)W0) ? row[x] - m : 0.f;
      }
    }
  }
  float a = alpha[0];
  _Float16* ob = outp + ((size_t)(n * H0 + oh) * W0 + ow) * 32;
#pragma clang loop unroll(disable)
  for (int g = 0; g < 4; g++) {
    float acc[8];
#pragma unroll
    for (int k = 0; k < 8; k++) acc[k] = bsm[g * 8 + k];
#pragma unroll
    for (int k = 0; k < 8; k++) {
      const float* wp = &wsm[(g * 8 + k) * 27];
#pragma unroll
      for (int j = 0; j < 27; j++) acc[k] += xv[j] * wp[j];
    }
    half8_t h;
#pragma unroll
    for (int k = 0; k < 8; k++) {
      float v = acc[k];
      v = v > 0.f ? v : a * v;
      h[k] = (_Float16)v;
    }
    *(half8_t*)(ob + g * 8) = h;
  }
}

template <int CIN, int COUT, int STRIDE, int TROWS>
__device__ __forceinline__ void conv_mfma_body(
    const _Float16* __restrict__ in, const _Float16* __restrict__ wT,
    const float* __restrict__ bias, const float* __restrict__ alpha,
    _Float16* __restrict__ outp, int Hin, int Win, int Hout, int Wout,
    int gx, int gy, int gz, int lb) {
  int T = gx * gy * gz;
  lb = (lb & 7) * (T >> 3) + (lb >> 3);
  int cob  = lb % gy;
  int n    = (lb / gy) % gz;
  int tile = lb / (gy * gz);
  int lane = threadIdx.x & 63, wave = threadIdx.x >> 6;
  int l15 = lane & 15, lhi = lane >> 4;
  int tiles_x = Wout >> 4;
  int tx = tile % tiles_x, ty = tile / tiles_x;
  int ow0 = tx << 4;
  int oh0 = ty * (4 * TROWS) + wave * TROWS;
  int co0 = cob * 32;
  floatx4 acc[2][TROWS] = {};
  const _Float16* ip = in + (size_t)n * Hin * Win * CIN;
  int x_base = (ow0 + l15) * STRIDE;
  int ybase = oh0 * STRIDE - 1;
  constexpr int NY = (TROWS - 1) * STRIDE + 3;
  const _Float16* wA = wT + (size_t)(co0 + l15) * CIN;
  const _Float16* wB = wT + (size_t)(co0 + 16 + l15) * CIN;
  for (int kc = 0; kc < CIN / 32; kc++) {
    int ci = kc * 32 + lhi * 8;
#pragma unroll
    for (int dxi = 0; dxi < 3; dxi++) {
      int x = x_base + dxi - 1;
      bool xv = (unsigned)x < (unsigned)Win;
      int xc = x < 0 ? 0 : (x >= Win ? Win - 1 : x);
      half8_t a0[3], a1[3];
#pragma unroll
      for (int dy = 0; dy < 3; dy++) {
        int q = dy * 3 + dxi;
        a0[dy] = *(const half8_t*)(wA + (size_t)q * COUT * CIN + ci);
        a1[dy] = *(const half8_t*)(wB + (size_t)q * COUT * CIN + ci);
      }
#pragma unroll
      for (int y6 = 0; y6 < NY; y6++) {
        int y = ybase + y6;
        if ((unsigned)y >= (unsigned)Hin) continue;   // wave-uniform; skip == zero-pad
        half8_t bf = *(const half8_t*)(ip + ((size_t)y * Win + xc) * CIN + ci);
        half8_t z = {};
        bf = xv ? bf : z;
#pragma unroll
        for (int dy = 0; dy < 3; dy++) {
          int tnum = y6 - dy;
          if (tnum < 0 || tnum % STRIDE != 0) continue;
          int t = tnum / STRIDE;
          if (t >= TROWS) continue;
          acc[0][t] = __builtin_amdgcn_mfma_f32_16x16x32_f16(a0[dy], bf, acc[0][t], 0, 0, 0);
          acc[1][t] = __builtin_amdgcn_mfma_f32_16x16x32_f16(a1[dy], bf, acc[1][t], 0, 0, 0);
        }
      }
    }
  }
  float aP = alpha[0];
#pragma unroll
  for (int h = 0; h < 2; h++) {
    float bia[4];
#pragma unroll
    for (int r = 0; r < 4; r++) bia[r] = bias[co0 + h * 16 + lhi * 4 + r];
#pragma unroll
    for (int t = 0; t < TROWS; t++) {
      half4_t hh;
#pragma unroll
      for (int r = 0; r < 4; r++) {
        float v = acc[h][t][r] + bia[r];
        v = v > 0.f ? v : aP * v;
        hh[r] = (_Float16)v;
      }
      *(half4_t*)(outp + (((size_t)n * Hout + oh0 + t) * Wout + ow0 + l15) * COUT +
                  co0 + h * 16 + lhi * 4) = hh;
    }
  }
}

__device__ __forceinline__ void d_scan_part(
    const unsigned* __restrict__ cnt, unsigned* __restrict__ tpre,
    unsigned* __restrict__ psum, int b) {
  int t = threadIdx.x;
  int off, sz, ci;
  chunk_map(b, off, sz, ci);
  int base = off + ci * CHUNK + t * 64;
  int lim = off + min(sz, (ci + 1) * CHUNK);
  unsigned s = 0;
  for (int j = 0; j < 64; j++) {
    int idx = base + j;
    if (idx < lim) s += cnt[idx];
  }
  __shared__ unsigned sm[256];
  sm[t] = s;
  __syncthreads();
  for (int o = 1; o < 256; o <<= 1) {
    unsigned v = (t >= o) ? sm[t - o] : 0u;
    __syncthreads();
    sm[t] += v;
    __syncthreads();
  }
  unsigned incl = sm[t];
  tpre[b * 256 + t] = incl - s;
  if (t == 255) psum[b] = incl;
}

__device__ __forceinline__ void pack_full_body(
    const float* __restrict__ img0, const float* __restrict__ img1,
    const float* __restrict__ msum, float invCnt,
    const _Float16* __restrict__ featN,
    const float* __restrict__ s01, const float* __restrict__ s10,
    const float* __restrict__ flowB,
    float* __restrict__ recs, unsigned* __restrict__ curs, int s) {
  constexpr int NCX = W0 + 1;
  constexpr int GX = HW0 / 256;
  int px = (s % GX) * 256 + (int)threadIdx.x;
  int b = (s / GX) % B;
  int dir = s / (GX * B);
  int nb = dir * B + b;
  float fx = flowB[((size_t)(nb * 2 + 0)) * HW0 + px];
  float fy = flowB[((size_t)(nb * 2 + 1)) * HW0 + px];
  int sw = px % W0, sh = px / W0;
  float tx = (float)sw + fx, ty = (float)sh + fy;
  float x0f = floorf(tx), y0f = floorf(ty);
  int x0 = (int)x0f, y0 = (int)y0f;
  if (x0 < -1 || x0 > W0 - 1 || y0 < -1 || y0 > H0 - 1) return;
  const float* imp = (dir ? img1 : img0) + (size_t)b * 3 * HW0;
  float m = msum[b] * invCnt;
  float im0 = imp[px] - m, im1 = imp[(size_t)HW0 + px] - m, im2 = imp[(size_t)2 * HW0 + px] - m;
  const float* sig = dir ? s10 : s01;
  float sg = sig[(size_t)b * HW0 + px];
  union { floatx4 f4[RS_F / 4]; unsigned u[RS_F]; } r;
  r.u[0] = f2h(im0, im1);
  r.u[1] = f2h(im2, sg);
  const floatx4* fp = (const floatx4*)(featN + ((size_t)nb * HW0 + px) * 32);
  union { floatx4 f; unsigned u[4]; } t;
#pragma unroll
  for (int j = 0; j < 4; j++) {
    t.f = fp[j];
    r.u[2 + 4 * j + 0] = t.u[0]; r.u[2 + 4 * j + 1] = t.u[1];
    r.u[2 + 4 * j + 2] = t.u[2]; r.u[2 + 4 * j + 3] = t.u[3];
  }
  r.u[18] = __float_as_uint(tx - x0f);
  r.u[19] = __float_as_uint(ty - y0f);
  unsigned slot = atomicAdd(&curs[nb * NC_F + (y0 + 1) * NCX + (x0 + 1)], 1u);
  floatx4* o = (floatx4*)(recs + (size_t)slot * RS_F);
#pragma unroll
  for (int j = 0; j < RS_F / 4; j++) o[j] = r.f4[j];
}

template <int C, int Hd, int Wd, int RS>
__device__ __forceinline__ void pack_feat_body(
    const _Float16* __restrict__ featN, const float* __restrict__ flowB,
    float* __restrict__ recs, unsigned* __restrict__ curs, int s) {
  constexpr int HWd = Hd * Wd;
  constexpr int NCX = Wd + 1;
  constexpr int NC  = (Wd + 1) * (Hd + 1);
  constexpr int GX = HWd / 256;
  int px = (s % GX) * 256 + (int)threadIdx.x;
  int b = (s / GX) % B;
  int dir = s / (GX * B);
  int nb = dir * B + b;
  float fx = flowB[((size_t)(nb * 2 + 0)) * HWd + px];
  float fy = flowB[((size_t)(nb * 2 + 1)) * HWd + px];
  int sw = px % Wd, sh = px / Wd;
  float tx = (float)sw + fx, ty = (float)sh + fy;
  float x0f = floorf(tx), y0f = floorf(ty);
  int x0 = (int)x0f, y0 = (int)y0f;
  if (x0 < -1 || x0 > Wd - 1 || y0 < -1 || y0 > Hd - 1) return;
  union { floatx4 f4[RS / 4]; unsigned u[RS]; } r;
  const floatx4* fp = (const floatx4*)(featN + ((size_t)nb * HWd + px) * C);
#pragma unroll
  for (int j = 0; j < C / 8; j++) r.f4[j] = fp[j];
  r.u[C / 2]     = __float_as_uint(tx - x0f);
  r.u[C / 2 + 1] = __float_as_uint(ty - y0f);
#pragma unroll
  for (int j = C / 2 + 2; j < RS; j++) r.u[j] = 0;
  unsigned slot = atomicAdd(&curs[nb * NC + (y0 + 1) * NCX + (x0 + 1)], 1u);
  floatx4* o = (floatx4*)(recs + (size_t)slot * RS);
#pragma unroll
  for (int j = 0; j < RS / 4; j++) o[j] = r.f4[j];
}

// ---- gathers: packed-f16 accumulation, channel-chunked for latency hiding ----

__device__ __forceinline__ void gather_full_body(
    const float* __restrict__ recs, const uint2* __restrict__ cs,
    float* __restrict__ outImg, float* __restrict__ outFeat,
    float* __restrict__ outSig, int lb) {
  constexpr int NCX = W0 + 1;
  constexpr int GX = HW0 / 256;
  constexpr int T = GX * B * 2 * 2;
  lb = (lb & 7) * (T >> 3) + (lb >> 3);
  int q = (lb % GX) * 256 + (int)threadIdx.x;
  int b = (lb / GX) % B;
  int dz = lb / (GX * B);
  int zh = dz & 1, dir = dz >> 1;        // zh: channel chunk, wave-uniform
  int nb = dir * B + b;
  int qx = q % W0, qy = q / W0;
  half2v ha[10];
#pragma unroll
  for (int j = 0; j < 10; j++) ha[j] = half2v{(_Float16)0.f, (_Float16)0.f};
  float dsum = 0.f;
  for (int ky = 0; ky < 2; ky++) {
    int cy = qy - 1 + ky;
    for (int kx = 0; kx < 2; kx++) {
      int cx = qx - 1 + kx;
      uint2 sc = cs[nb * NC_F + (cy + 1) * NCX + (cx + 1)];
      unsigned s0 = sc.x, cn = sc.y;
      for (unsigned s = s0; s < s0 + cn; s++) {
        const float* rp = recs + (size_t)s * RS_F;
        float2 hd = *(const float2*)(rp + 18);
        float wx = kx ? (1.f - hd.x) : hd.x;
        float wy = ky ? (1.f - hd.y) : hd.y;
        float w = wx * wy;
        dsum += w;
        _Float16 wh = (_Float16)w;
        half2v ww = {wh, wh};
        if (zh == 0) {
          union { floatx4 f; half2v h[4]; } t0, t1;
          t0.f = *(const floatx4*)(rp);
          t1.f = *(const floatx4*)(rp + 4);
#pragma unroll
          for (int j = 0; j < 4; j++) { ha[j] += t0.h[j] * ww; ha[4 + j] += t1.h[j] * ww; }
        } else {
          union { floatx4 f; half2v h[4]; } t2, t3;
          union { float2 f; half2v h[2]; } t4;
          t2.f = *(const floatx4*)(rp + 8);
          t3.f = *(const floatx4*)(rp + 12);
          t4.f = *(const float2*)(rp + 16);
#pragma unroll
          for (int j = 0; j < 4; j++) { ha[j] += t2.h[j] * ww; ha[4 + j] += t3.h[j] * ww; }
          ha[8] += t4.h[0] * ww;
          ha[9] += t4.h[1] * ww;
        }
      }
    }
  }
  float inv = 1.f / fmaxf(dsum, 1e-7f);
  if (zh == 0) {
    // words 0..7: (im0,im1) (im2,sig) feat0..11
    outImg[((size_t)(b * 6 + dir * 3 + 0)) * HW0 + q] = (float)ha[0][0] * inv;
    outImg[((size_t)(b * 6 + dir * 3 + 1)) * HW0 + q] = (float)ha[0][1] * inv;
    outImg[((size_t)(b * 6 + dir * 3 + 2)) * HW0 + q] = (float)ha[1][0] * inv;
    outSig[((size_t)(b * 2 + dir)) * HW0 + q]         = (float)ha[1][1] * inv;
#pragma unroll
    for (int j = 0; j < 6; j++) {
      outFeat[((size_t)(b * 64 + dir * 32 + 2 * j + 0)) * HW0 + q] = (float)ha[2 + j][0] * inv;
      outFeat[((size_t)(b * 64 + dir * 32 + 2 * j + 1)) * HW0 + q] = (float)ha[2 + j][1] * inv;
    }
  } else {
    // words 8..17: feat12..31
#pragma unroll
    for (int j = 0; j < 10; j++) {
      outFeat[((size_t)(b * 64 + dir * 32 + 12 + 2 * j + 0)) * HW0 + q] = (float)ha[j][0] * inv;
      outFeat[((size_t)(b * 64 + dir * 32 + 12 + 2 * j + 1)) * HW0 + q] = (float)ha[j][1] * inv;
    }
  }
}

template <int C, int Hd, int Wd, int RS>
__device__ __forceinline__ void gather_feat_body(
    const float* __restrict__ recs, const uint2* __restrict__ cs,
    float* __restrict__ outF, int lb) {
  constexpr int HWd = Hd * Wd;
  constexpr int NCX = Wd + 1;
  constexpr int NC  = (Wd + 1) * (Hd + 1);
  constexpr int GX = HWd / 256;
  constexpr int Z = C / 16;              // 16-channel chunks
  constexpr int T = GX * B * 2 * Z;
  lb = (lb & 7) * (T >> 3) + (lb >> 3);
  int q = (lb % GX) * 256 + (int)threadIdx.x;
  int b = (lb / GX) % B;
  int dz = lb / (GX * B);
  int z = dz % Z, dir = dz / Z;
  int c0 = z * 16;
  int nb = dir * B + b;
  int qx = q % Wd, qy = q / Wd;
  half2v ha[8];
#pragma unroll
  for (int j = 0; j < 8; j++) ha[j] = half2v{(_Float16)0.f, (_Float16)0.f};
  float dsum = 0.f;
  for (int ky = 0; ky < 2; ky++) {
    int cy = qy - 1 + ky;
    for (int kx = 0; kx < 2; kx++) {
      int cx = qx - 1 + kx;
      uint2 sc = cs[nb * NC + (cy + 1) * NCX + (cx + 1)];
      unsigned s0 = sc.x, cn = sc.y;
      for (unsigned s = s0; s < s0 + cn; s++) {
        const float* rp = recs + (size_t)s * RS;
        union { floatx4 f; half2v h[4]; } t0, t1;
        t0.f = *(const floatx4*)(rp + 8 * z);
        t1.f = *(const floatx4*)(rp + 8 * z + 4);
        float2 hd = *(const float2*)(rp + C / 2);
        float wx = kx ? (1.f - hd.x) : hd.x;
        float wy = ky ? (1.f - hd.y) : hd.y;
        float w = wx * wy;
        dsum += w;
        _Float16 wh = (_Float16)w;
        half2v ww = {wh, wh};
#pragma unroll
        for (int j = 0; j < 4; j++) { ha[j] += t0.h[j] * ww; ha[4 + j] += t1.h[j] * ww; }
      }
    }
  }
  float inv = 1.f / fmaxf(dsum, 1e-7f);
  size_t obase = ((size_t)(b * 2 * C + dir * C + c0)) * HWd + q;
#pragma unroll
  for (int j = 0; j < 8; j++) {
    outF[obase + (size_t)(2 * j + 0) * HWd] = (float)ha[j][0] * inv;
    outF[obase + (size_t)(2 * j + 1) * HWd] = (float)ha[j][1] * inv;
  }
}

// ================= merged kernels =================

__global__ __launch_bounds__(256) void k_front(
    const float* f01, const float* s01, const float* f10, const float* s10,
    float* flowF, unsigned* cntF,
    const float* img0, const float* img1, float* msum,
    const float* w2, const float* w3, const float* w4, const float* w5, const float* w6,
    _Float16* o2, _Float16* o3, _Float16* o4, _Float16* o5, _Float16* o6) {
  int f = blockIdx.x;
  if (f < NB_IF) d_interflow2(f01, s01, f10, s10, flowF, cntF, f);
  else if (f < NB_IF + NB_MEAN) d_mean(img0, img1, msum, f - NB_IF);
  else d_wtrans(w2, w3, w4, w5, w6, o2, o3, o4, o5, o6, f - NB_IF - NB_MEAN);
}

__global__ __launch_bounds__(256) void k_down_conv1(
    const float* flowF, float* flowH, unsigned* cntH, float* flowQ, unsigned* cntQ,
    const float* img0, const float* img1, const float* msum, float invCnt,
    const float* w1, const float* b1, const float* a1, _Float16* Ah) {
  int f = blockIdx.x;
  if (f < NB_DH) d_downflow2<2, H1, W1>(flowF, flowH, cntH, f);
  else if (f < NB_DH + NB_DQ) d_downflow2<4, H2, W2>(flowF, flowQ, cntQ, f - NB_DH);
  else d_conv1(img0, img1, msum, invCnt, w1, b1, a1, Ah, f - NB_DH - NB_DQ);
}

__global__ __launch_bounds__(256) void k_scan_conv2(
    const unsigned* cntAll, unsigned* tpre, unsigned* psum,
    const _Float16* Ah, const _Float16* wt2, const float* b2, const float* a2,
    _Float16* Bh) {
  int f = blockIdx.x;
  if (f < NCHUNKS) d_scan_part(cntAll, tpre, psum, f);
  else conv_mfma_body<32, 32, 1, 8>(Ah, wt2, b2, a2, Bh, H0, W0, H0, W0,
                                    224, 1, 8, f - NCHUNKS);
}

__global__ __launch_bounds__(256) void k_scan_apply(
    const unsigned* __restrict__ cnt, const unsigned* __restrict__ tpre,
    const unsigned* __restrict__ psum,
    uint2* __restrict__ cs, unsigned* __restrict__ curs) {
  int b = blockIdx.x, t = threadIdx.x;
  int off, sz, ci;
  chunk_map(b, off, sz, ci);
  __shared__ unsigned cbs;
  if (t == 0) {
    int first = (off == 0) ? 0 : (off == SZ_F ? NCH_F : NCH_F + NCH_H);
    unsigned c = 0;
    for (int k = first; k < first + ci; k++) c += psum[k];
    cbs = c;
  }
  __syncthreads();
  int base = off + ci * CHUNK + t * 64;
  int lim = off + min(sz, (ci + 1) * CHUNK);
  unsigned run = cbs + tpre[b * 256 + t];
  for (int j = 0; j < 64; j++) {
    int idx = base + j;
    if (idx < lim) {
      unsigned c = cnt[idx];
      cs[idx] = make_uint2(run, c);
      curs[idx] = run;
      run += c;
    }
  }
}

__global__ __launch_bounds__(256) void k_packF_conv3(
    const float* img0, const float* img1, const float* msum, float invCnt,
    const _Float16* Bh, const float* s01, const float* s10, const float* flowF,
    float* recs, unsigned* cursF,
    const _Float16* wt3, const float* b3, const float* a3, _Float16* Ah) {
  int f = blockIdx.x;
  if (f < NB_PF)
    pack_full_body(img0, img1, msum, invCnt, Bh, s01, s10, flowF, recs, cursF, f);
  else
    conv_mfma_body<32, 64, 2, 4>(Bh, wt3, b3, a3, Ah, H0, W0, H1, W1,
                                 112, 2, 8, f - NB_PF);
}

__global__ __launch_bounds__(256) void k_gatherF_conv4(
    const float* recs, const uint2* csF,
    float* outImg, float* outFeat, float* outSig,
    const _Float16* Ah, const _Float16* wt4, const float* b4, const float* a4,
    _Float16* Bh) {
  int f = blockIdx.x;
  if (f < NB_GF)
    gather_full_body(recs, csF, outImg, outFeat, outSig, f);
  else
    conv_mfma_body<64, 64, 1, 8>(Ah, wt4, b4, a4, Bh, H1, W1, H1, W1,
                                 56, 2, 8, f - NB_GF);
}

__global__ __launch_bounds__(256) void k_packH_conv5(
    const _Float16* Bh, const float* flowH, float* recs, unsigned* cursH,
    const _Float16* wt5, const float* b5, const float* a5, _Float16* Ah) {
  int f = blockIdx.x;
  if (f < NB_PH)
    pack_feat_body<64, H1, W1, RS_H>(Bh, flowH, recs, cursH, f);
  else
    conv_mfma_body<64, 96, 2, 4>(Bh, wt5, b5, a5, Ah, H1, W1, H2, W2,
                                 28, 3, 8, f - NB_PH);
}

__global__ __launch_bounds__(256) void k_gatherH_conv6(
    const float* recs, const uint2* csH, float* outF2,
    const _Float16* Ah, const _Float16* wt6, const float* b6, const float* a6,
    _Float16* Bh) {
  int f = blockIdx.x;
  if (f < NB_GH)
    gather_feat_body<64, H1, W1, RS_H>(recs, csH, outF2, f);
  else
    conv_mfma_body<96, 96, 1, 4>(Ah, wt6, b6, a6, Bh, H2, W2, H2, W2,
                                 28, 3, 8, f - NB_GH);
}

__global__ __launch_bounds__(256) void k_packQ(
    const _Float16* Bh, const float* flowQ, float* recs, unsigned* cursQ) {
  pack_feat_body<96, H2, W2, RS_Q>(Bh, flowQ, recs, cursQ, blockIdx.x);
}

__global__ __launch_bounds__(256) void k_gatherQ(
    const float* recs, const uint2* csQ, float* outF3) {
  gather_feat_body<96, H2, W2, RS_Q>(recs, csQ, outF3, blockIdx.x);
}

extern "C" void kernel_launch(void* const* d_in, const int* in_sizes, int n_in,
                              void* d_out, int out_size, void* d_ws, size_t ws_size,
                              hipStream_t stream) {
  (void)in_sizes; (void)n_in; (void)out_size;
  if (ws_size < WS_FLOATS * sizeof(float)) return;

  const float* img0    = (const float*)d_in[0];
  const float* img1    = (const float*)d_in[1];
  const float* flow01  = (const float*)d_in[2];
  const float* sigma01 = (const float*)d_in[3];
  const float* flow10  = (const float*)d_in[4];
  const float* sigma10 = (const float*)d_in[5];
  const float* wp[6]; const float* bp[6]; const float* ap[6];
  for (int i = 0; i < 6; i++) {
    wp[i] = (const float*)(d_in[6 + 3 * i]);
    bp[i] = (const float*)(d_in[7 + 3 * i]);
    ap[i] = (const float*)(d_in[8 + 3 * i]);
  }
  float* ws  = (float*)d_ws;
  float* out = (float*)d_out;

  unsigned* cntAll  = (unsigned*)(ws + OFF_CNT);
  unsigned* cntF = cntAll;
  unsigned* cntH = cntAll + SZ_F;
  unsigned* cntQ = cntAll + SZ_F + SZ_H;
  uint2*    csAll = (uint2*)(ws + OFF_CS);
  uint2*    csF = csAll, *csH = csAll + SZ_F, *csQ = csAll + SZ_F + SZ_H;
  unsigned* cursAll  = (unsigned*)(ws + OFF_CURS);
  unsigned* cursF = cursAll, *cursH = cursAll + SZ_F, *cursQ = cursAll + SZ_F + SZ_H;
  unsigned* tpre  = (unsigned*)(ws + OFF_TPRE);
  unsigned* psum  = (unsigned*)(ws + OFF_PSUM);
  float*    recs  = ws + OFF_RECS;
  _Float16* Ah = (_Float16*)(ws + OFF_BUFA);
  _Float16* Bh = (_Float16*)(ws + OFF_BUFB);
  _Float16* wt[5] = {(_Float16*)(ws + OFF_WT2), (_Float16*)(ws + OFF_WT3),
                     (_Float16*)(ws + OFF_WT4), (_Float16*)(ws + OFF_WT5),
                     (_Float16*)(ws + OFF_WT6)};
  float* flowF = ws + OFF_FLOW;
  float* flowH = ws + OFF_FLH;
  float* flowQ = ws + OFF_FLQ;

  const float invCnt = 1.f / (6.f * (float)HW0);

  dim3 blk(256);

  // 0: fast zero of mean + cnt regions
  k_zero<<<dim3(1024), blk, 0, stream>>>((floatx4*)ws, (int)(ZERO_FLOATS / 4));

  // 1: interflow || mean || wtrans
  k_front<<<dim3(NB_IF + NB_MEAN + NB_WT), blk, 0, stream>>>(
      flow01, sigma01, flow10, sigma10, flowF, cntF,
      img0, img1, ws + OFF_MEAN,
      wp[1], wp[2], wp[3], wp[4], wp[5], wt[0], wt[1], wt[2], wt[3], wt[4]);

  // 2: downflowH || downflowQ || conv1
  k_down_conv1<<<dim3(NB_DH + NB_DQ + NB_C1), blk, 0, stream>>>(
      flowF, flowH, cntH, flowQ, cntQ,
      img0, img1, ws + OFF_MEAN, invCnt, wp[0], bp[0], ap[0], Ah);

  // 3: scan_part || conv2
  k_scan_conv2<<<dim3(NCHUNKS + NB_C2), blk, 0, stream>>>(
      cntAll, tpre, psum, Ah, wt[0], bp[1], ap[1], Bh);

  // 4: scan_apply
  k_scan_apply<<<dim3(NCHUNKS), blk, 0, stream>>>(cntAll, tpre, psum, csAll, cursAll);

  // 5: pack_full || conv3
  k_packF_conv3<<<dim3(NB_PF + NB_C3), blk, 0, stream>>>(
      img0, img1, ws + OFF_MEAN, invCnt, Bh, sigma01, sigma10, flowF,
      recs, cursF, wt[1], bp[2], ap[2], Ah);

  // 6: gather_full (2 ch-chunks) || conv4
  k_gatherF_conv4<<<dim3(NB_GF + NB_C4), blk, 0, stream>>>(
      recs, csF, out + O_IMG, out + O_F1, out + O_SIG,
      Ah, wt[2], bp[3], ap[3], Bh);

  // 7: pack_H || conv5
  k_packH_conv5<<<dim3(NB_PH + NB_C5), blk, 0, stream>>>(
      Bh, flowH, recs, cursH, wt[3], bp[4], ap[4], Ah);

  // 8: gather_H (16-ch chunks) || conv6
  k_gatherH_conv6<<<dim3(NB_GH + NB_C6), blk, 0, stream>>>(
      recs, csH, out + O_F2, Ah, wt[4], bp[5], ap[5], Bh);

  // 9: pack_Q ; 10: gather_Q (16-ch chunks)
  k_packQ<<<dim3((HW2 / 256) * B * 2), blk, 0, stream>>>(Bh, flowQ, recs, cursQ);
  k_gatherQ<<<dim3((HW2 / 256) * B * 2 * 6), blk, 0, stream>>>(recs, csQ, out + O_F3);
}

// Round 17
// 560.309 us; speedup vs baseline: 1.1659x; 1.1659x over previous
//
#include <hip/hip_runtime.h>
#include <hip/hip_fp16.h>

static constexpr int B  = 4;
static constexpr int H0 = 256, W0 = 448, HW0 = H0 * W0;   // full
static constexpr int H1 = 128, W1 = 224, HW1 = H1 * W1;   // half
static constexpr int H2 = 64,  W2 = 112, HW2 = H2 * W2;   // quarter

typedef _Float16 half8_t __attribute__((ext_vector_type(8)));
typedef _Float16 half4_t __attribute__((ext_vector_type(4)));
typedef _Float16 half2v  __attribute__((ext_vector_type(2)));
typedef float floatx4 __attribute__((ext_vector_type(4)));

static constexpr int NC_F = (W0 + 1) * (H0 + 1);
static constexpr int NC_H = (W1 + 1) * (H1 + 1);
static constexpr int NC_Q = (W2 + 1) * (H2 + 1);

static constexpr int RS_F = 20;
static constexpr int RS_H = 36;
static constexpr int RS_Q = 52;

static constexpr int SZ_F = 2 * B * NC_F;
static constexpr int SZ_H = 2 * B * NC_H;
static constexpr int SZ_Q = 2 * B * NC_Q;
static constexpr int CNT_TOTAL = SZ_F + SZ_H + SZ_Q;

static constexpr int CHUNK = 16384;
static constexpr int NCH_F = (SZ_F + CHUNK - 1) / CHUNK;
static constexpr int NCH_H = (SZ_H + CHUNK - 1) / CHUNK;
static constexpr int NCH_Q = (SZ_Q + CHUNK - 1) / CHUNK;
static constexpr int NCHUNKS = NCH_F + NCH_H + NCH_Q;     // 76

// ---------------- workspace layout (floats) ----------------
static constexpr size_t OFF_MEAN   = 0;
static constexpr size_t OFF_CNT    = 256;
static constexpr size_t ZERO_FLOATS = OFF_CNT + CNT_TOTAL;   // divisible by 4
static constexpr size_t OFF_BUFA   = ZERO_FLOATS;
static constexpr size_t OFF_BUFB   = OFF_BUFA + (size_t)4 * 32 * HW0;
static constexpr size_t OFF_FLOW   = OFF_BUFB + (size_t)4 * 32 * HW0;
static constexpr size_t OFF_FLH    = OFF_FLOW + (size_t)2 * B * 2 * HW0;
static constexpr size_t OFF_FLQ    = OFF_FLH + (size_t)2 * B * 2 * HW1;
static constexpr size_t OFF_WT2 = OFF_FLQ + (size_t)2 * B * 2 * HW2;
static constexpr size_t OFF_WT3 = OFF_WT2 + 4608;
static constexpr size_t OFF_WT4 = OFF_WT3 + 9216;
static constexpr size_t OFF_WT5 = OFF_WT4 + 18432;
static constexpr size_t OFF_WT6 = OFF_WT5 + 27648;
static constexpr size_t OFF_CS   = OFF_WT6 + 41472;
static constexpr size_t OFF_CURS = OFF_CS + (size_t)2 * CNT_TOTAL;
static constexpr size_t OFF_TPRE = OFF_CURS + CNT_TOTAL;
static constexpr size_t OFF_PSUM = OFF_TPRE + (size_t)NCHUNKS * 256;
static constexpr size_t OFF_RECS = OFF_PSUM + 128;
static constexpr size_t WS_FLOATS = OFF_RECS + (size_t)2 * B * HW0 * RS_F;

// ---------------- output layout (floats) ----------------
static constexpr size_t O_IMG = 0;
static constexpr size_t O_F1  = O_IMG + (size_t)B * 6 * HW0;
static constexpr size_t O_F2  = O_F1  + (size_t)B * 64 * HW0;
static constexpr size_t O_F3  = O_F2  + (size_t)B * 128 * HW1;
static constexpr size_t O_SIG = O_F3  + (size_t)B * 192 * HW2;

// sub-grid block counts (all multiples of 8 -> bijective XCD swizzle)
static constexpr int NB_IF = 2 * B * HW0 / 256;   // 3584
static constexpr int NB_MEAN = 32 * B;            // 128
static constexpr int NB_WT = (202752 + 255) / 256;// 792
static constexpr int NB_DH = 2 * B * HW1 / 256;   // 896
static constexpr int NB_DQ = 2 * B * HW2 / 256;   // 224
static constexpr int NB_C1 = 448 * 8;             // 3584
static constexpr int NB_C2 = 224 * 8;             // 1792
static constexpr int NB_PF = (HW0 / 256) * B * 2; // 3584
static constexpr int NB_C3 = 112 * 2 * 8;         // 1792
static constexpr int NB_GF = NB_PF;               // 3584
static constexpr int NB_C4 = 56 * 2 * 8;          // 896
static constexpr int NB_PH = (HW1 / 256) * B * 2; // 896
static constexpr int NB_C5 = 28 * 3 * 8;          // 672
static constexpr int NB_GH = (HW1 / 256) * B * 4; // 1792 (Z=2 x 2 dirs)
static constexpr int NB_C6 = 28 * 3 * 8;          // 672

__device__ inline unsigned f2h(float lo, float hi) {
  __half2 h = __floats2half2_rn(lo, hi);
  return *reinterpret_cast<unsigned*>(&h);
}

__device__ inline void chunk_map(int b, int& off, int& sz, int& ci) {
  if (b < NCH_F)              { off = 0;           sz = SZ_F; ci = b; }
  else if (b < NCH_F + NCH_H) { off = SZ_F;        sz = SZ_H; ci = b - NCH_F; }
  else                        { off = SZ_F + SZ_H; sz = SZ_Q; ci = b - NCH_F - NCH_H; }
}

// ---------------- fast zero ----------------
__global__ __launch_bounds__(256) void k_zero(floatx4* __restrict__ p, int n4) {
  floatx4 z = {};
  for (int i = blockIdx.x * 256 + threadIdx.x; i < n4; i += gridDim.x * 256)
    p[i] = z;
}

// ================= device bodies =================

__device__ __forceinline__ void d_mean(const float* __restrict__ img0,
                                       const float* __restrict__ img1,
                                       float* __restrict__ msum, int s) {
  const int perImg = 3 * HW0;
  int bx = s & 31, b = s >> 5;
  float acc = 0.f;
  int tot = 2 * perImg;
  for (int i = bx * 256 + threadIdx.x; i < tot; i += 32 * 256) {
    acc += (i < perImg) ? img0[(size_t)b * perImg + i] : img1[(size_t)b * perImg + (i - perImg)];
  }
#pragma unroll
  for (int o = 32; o > 0; o >>= 1) acc += __shfl_down(acc, o);
  __shared__ float red[4];
  int lane = threadIdx.x & 63, wid = threadIdx.x >> 6;
  if (lane == 0) red[wid] = acc;
  __syncthreads();
  if (threadIdx.x == 0) atomicAdd(&msum[b], red[0] + red[1] + red[2] + red[3]);
}

__device__ __forceinline__ void d_interflow2(
    const float* __restrict__ f01, const float* __restrict__ s01,
    const float* __restrict__ f10, const float* __restrict__ s10,
    float* __restrict__ outBase, unsigned* __restrict__ cntF, int s) {
  constexpr int NCX = W0 + 1;
  int i = s * 256 + (int)threadIdx.x;
  if (i >= 2 * B * HW0) return;
  int nb = i / HW0;
  int px = i - nb * HW0;
  int dir = nb >> 2, b = nb & 3;
  const float* flo = dir ? f10 : f01;
  const float* sigma = dir ? s10 : s01;
  float fx = flo[((size_t)(b * 2 + 0)) * HW0 + px];
  float fy = flo[((size_t)(b * 2 + 1)) * HW0 + px];
  float sg = sigma[(size_t)b * HW0 + px];
  float ftx, fty;
  if (fabsf(sg) < 0.01f) {
    ftx = 0.5f * fx; fty = 0.5f * fy;
  } else {
    float g = (1.f - sqrtf(fmaxf(0.f, 1.f - sg * sg))) / (2.f * sg);
    ftx = 0.5f * fx - g * fy;
    fty = 0.5f * fy + g * fx;
  }
  outBase[((size_t)(nb * 2 + 0)) * HW0 + px] = ftx;
  outBase[((size_t)(nb * 2 + 1)) * HW0 + px] = fty;
  int sw = px % W0, sh = px / W0;
  float tx = (float)sw + ftx, ty = (float)sh + fty;
  int x0 = (int)floorf(tx), y0 = (int)floorf(ty);
  if (x0 >= -1 && x0 <= W0 - 1 && y0 >= -1 && y0 <= H0 - 1)
    atomicAdd(&cntF[nb * NC_F + (y0 + 1) * NCX + (x0 + 1)], 1u);
}

template <int F, int Hd, int Wd>
__device__ __forceinline__ void d_downflow2(
    const float* __restrict__ in, float* __restrict__ out,
    unsigned* __restrict__ cnt, int s) {
  constexpr int HWd = Hd * Wd;
  constexpr int NCX = Wd + 1;
  constexpr int NC  = (Wd + 1) * (Hd + 1);
  int i = s * 256 + (int)threadIdx.x;
  if (i >= 2 * B * HWd) return;
  int nb = i / HWd;
  int px = i - nb * HWd;
  int ow = px % Wd, oh = px / Wd;
  float cy = (oh + 0.5f) * F - 0.5f;
  float cx = (ow + 0.5f) * F - 0.5f;
  int ylo = (int)floorf(cy) - F + 1;
  int xlo = (int)floorf(cx) - F + 1;
  const float* ipx = in + ((size_t)(nb * 2 + 0)) * HW0;
  const float* ipy = in + ((size_t)(nb * 2 + 1)) * HW0;
  float ax = 0.f, ay = 0.f, wn = 0.f;
  for (int jy = 0; jy < 2 * F; jy++) {
    int y = ylo + jy;
    if ((unsigned)y >= (unsigned)H0) continue;
    float wy = 1.f - fabsf((float)y - cy) / (float)F;
    for (int jx = 0; jx < 2 * F; jx++) {
      int x = xlo + jx;
      if ((unsigned)x >= (unsigned)W0) continue;
      float wx = 1.f - fabsf((float)x - cx) / (float)F;
      float ww = wy * wx;
      ax += ww * ipx[(size_t)y * W0 + x];
      ay += ww * ipy[(size_t)y * W0 + x];
      wn += ww;
    }
  }
  float sc = 1.f / (wn * (float)F);
  float fx = ax * sc, fy = ay * sc;
  out[((size_t)(nb * 2 + 0)) * HWd + px] = fx;
  out[((size_t)(nb * 2 + 1)) * HWd + px] = fy;
  float tx = (float)ow + fx, ty = (float)oh + fy;
  int x0 = (int)floorf(tx), y0 = (int)floorf(ty);
  if (x0 >= -1 && x0 <= Wd - 1 && y0 >= -1 && y0 <= Hd - 1)
    atomicAdd(&cnt[nb * NC + (y0 + 1) * NCX + (x0 + 1)], 1u);
}

__device__ __forceinline__ void d_wtrans(
    const float* __restrict__ w2, const float* __restrict__ w3,
    const float* __restrict__ w4, const float* __restrict__ w5,
    const float* __restrict__ w6,
    _Float16* __restrict__ o2, _Float16* __restrict__ o3,
    _Float16* __restrict__ o4, _Float16* __restrict__ o5,
    _Float16* __restrict__ o6, int s) {
  int i = s * 256 + (int)threadIdx.x;
  const float* w; _Float16* o; int COUT, CIN, base;
  if      (i <   9216) { w = w2; o = o2; COUT = 32; CIN = 32; base = 0; }
  else if (i <  27648) { w = w3; o = o3; COUT = 64; CIN = 32; base = 9216; }
  else if (i <  64512) { w = w4; o = o4; COUT = 64; CIN = 64; base = 27648; }
  else if (i < 119808) { w = w5; o = o5; COUT = 96; CIN = 64; base = 64512; }
  else if (i < 202752) { w = w6; o = o6; COUT = 96; CIN = 96; base = 119808; }
  else return;
  int j = i - base;
  int q = j % 9;
  int rest = j / 9;
  int ci = rest % CIN;
  int co = rest / CIN;
  o[((size_t)q * COUT + co) * CIN + ci] = (_Float16)w[j];
}

__device__ __forceinline__ void d_conv1(
    const float* __restrict__ img0, const float* __restrict__ img1,
    const float* __restrict__ msum, float invCnt,
    const float* __restrict__ wgt, const float* __restrict__ bias,
    const float* __restrict__ alpha, _Float16* __restrict__ outp, int s) {
  __shared__ float wsm[32 * 27];
  __shared__ float bsm[32];
  int bx = s % 448, n = s / 448;
  for (int i = threadIdx.x; i < 32 * 27; i += 256) wsm[i] = wgt[i];
  if (threadIdx.x < 32) bsm[threadIdx.x] = bias[threadIdx.x];
  __syncthreads();
  int b = n & 3;
  const float* ip = (n < 4 ? img0 : img1) + (size_t)b * 3 * HW0;
  float m = msum[b] * invCnt;
  int tx = bx % 7, ty = bx / 7;
  int ow = tx * 64 + (threadIdx.x & 63);
  int oh = ty * 4 + (threadIdx.x >> 6);
  float xv[27];
#pragma unroll
  for (int ci = 0; ci < 3; ci++) {
    const float* iq = ip + (size_t)ci * HW0;
#pragma unroll
    for (int ky = 0; ky < 3; ky++) {
      int y = oh - 1 + ky;
      bool yv = (unsigned)y < (unsigned)H0;
      const float* row = iq + (size_t)y * W0;
#pragma unroll
      for (int kx = 0; kx < 3; kx++) {
        int x = ow - 1 + kx;
        xv[ci * 9 + ky * 3 + kx] = (yv && (unsigned)x < (unsigned)W0) ? row[x] - m : 0.f;
      }
    }
  }
  float a = alpha[0];
  _Float16* ob = outp + ((size_t)(n * H0 + oh) * W0 + ow) * 32;
#pragma clang loop unroll(disable)
  for (int g = 0; g < 4; g++) {
    float acc[8];
#pragma unroll
    for (int k = 0; k < 8; k++) acc[k] = bsm[g * 8 + k];
#pragma unroll
    for (int k = 0; k < 8; k++) {
      const float* wp = &wsm[(g * 8 + k) * 27];
#pragma unroll
      for (int j = 0; j < 27; j++) acc[k] += xv[j] * wp[j];
    }
    half8_t h;
#pragma unroll
    for (int k = 0; k < 8; k++) {
      float v = acc[k];
      v = v > 0.f ? v : a * v;
      h[k] = (_Float16)v;
    }
    *(half8_t*)(ob + g * 8) = h;
  }
}

template <int CIN, int COUT, int STRIDE, int TROWS>
__device__ __forceinline__ void conv_mfma_body(
    const _Float16* __restrict__ in, const _Float16* __restrict__ wT,
    const float* __restrict__ bias, const float* __restrict__ alpha,
    _Float16* __restrict__ outp, int Hin, int Win, int Hout, int Wout,
    int gx, int gy, int gz, int lb) {
  int T = gx * gy * gz;
  lb = (lb & 7) * (T >> 3) + (lb >> 3);
  int cob  = lb % gy;
  int n    = (lb / gy) % gz;
  int tile = lb / (gy * gz);
  int lane = threadIdx.x & 63, wave = threadIdx.x >> 6;
  int l15 = lane & 15, lhi = lane >> 4;
  int tiles_x = Wout >> 4;
  int tx = tile % tiles_x, ty = tile / tiles_x;
  int ow0 = tx << 4;
  int oh0 = ty * (4 * TROWS) + wave * TROWS;
  int co0 = cob * 32;
  floatx4 acc[2][TROWS] = {};
  const _Float16* ip = in + (size_t)n * Hin * Win * CIN;
  int x_base = (ow0 + l15) * STRIDE;
  int ybase = oh0 * STRIDE - 1;
  constexpr int NY = (TROWS - 1) * STRIDE + 3;
  const _Float16* wA = wT + (size_t)(co0 + l15) * CIN;
  const _Float16* wB = wT + (size_t)(co0 + 16 + l15) * CIN;
  for (int kc = 0; kc < CIN / 32; kc++) {
    int ci = kc * 32 + lhi * 8;
#pragma unroll
    for (int dxi = 0; dxi < 3; dxi++) {
      int x = x_base + dxi - 1;
      bool xv = (unsigned)x < (unsigned)Win;
      int xc = x < 0 ? 0 : (x >= Win ? Win - 1 : x);
      half8_t a0[3], a1[3];
#pragma unroll
      for (int dy = 0; dy < 3; dy++) {
        int q = dy * 3 + dxi;
        a0[dy] = *(const half8_t*)(wA + (size_t)q * COUT * CIN + ci);
        a1[dy] = *(const half8_t*)(wB + (size_t)q * COUT * CIN + ci);
      }
#pragma unroll
      for (int y6 = 0; y6 < NY; y6++) {
        int y = ybase + y6;
        if ((unsigned)y >= (unsigned)Hin) continue;   // wave-uniform; skip == zero-pad
        half8_t bf = *(const half8_t*)(ip + ((size_t)y * Win + xc) * CIN + ci);
        half8_t z = {};
        bf = xv ? bf : z;
#pragma unroll
        for (int dy = 0; dy < 3; dy++) {
          int tnum = y6 - dy;
          if (tnum < 0 || tnum % STRIDE != 0) continue;
          int t = tnum / STRIDE;
          if (t >= TROWS) continue;
          acc[0][t] = __builtin_amdgcn_mfma_f32_16x16x32_f16(a0[dy], bf, acc[0][t], 0, 0, 0);
          acc[1][t] = __builtin_amdgcn_mfma_f32_16x16x32_f16(a1[dy], bf, acc[1][t], 0, 0, 0);
        }
      }
    }
  }
  float aP = alpha[0];
#pragma unroll
  for (int h = 0; h < 2; h++) {
    float bia[4];
#pragma unroll
    for (int r = 0; r < 4; r++) bia[r] = bias[co0 + h * 16 + lhi * 4 + r];
#pragma unroll
    for (int t = 0; t < TROWS; t++) {
      half4_t hh;
#pragma unroll
      for (int r = 0; r < 4; r++) {
        float v = acc[h][t][r] + bia[r];
        v = v > 0.f ? v : aP * v;
        hh[r] = (_Float16)v;
      }
      *(half4_t*)(outp + (((size_t)n * Hout + oh0 + t) * Wout + ow0 + l15) * COUT +
                  co0 + h * 16 + lhi * 4) = hh;
    }
  }
}

__device__ __forceinline__ void d_scan_part(
    const unsigned* __restrict__ cnt, unsigned* __restrict__ tpre,
    unsigned* __restrict__ psum, int b) {
  int t = threadIdx.x;
  int off, sz, ci;
  chunk_map(b, off, sz, ci);
  int base = off + ci * CHUNK + t * 64;
  int lim = off + min(sz, (ci + 1) * CHUNK);
  unsigned s = 0;
  for (int j = 0; j < 64; j++) {
    int idx = base + j;
    if (idx < lim) s += cnt[idx];
  }
  __shared__ unsigned sm[256];
  sm[t] = s;
  __syncthreads();
  for (int o = 1; o < 256; o <<= 1) {
    unsigned v = (t >= o) ? sm[t - o] : 0u;
    __syncthreads();
    sm[t] += v;
    __syncthreads();
  }
  unsigned incl = sm[t];
  tpre[b * 256 + t] = incl - s;
  if (t == 255) psum[b] = incl;
}

__device__ __forceinline__ void pack_full_body(
    const float* __restrict__ img0, const float* __restrict__ img1,
    const float* __restrict__ msum, float invCnt,
    const _Float16* __restrict__ featN,
    const float* __restrict__ s01, const float* __restrict__ s10,
    const float* __restrict__ flowB,
    float* __restrict__ recs, unsigned* __restrict__ curs, int s) {
  constexpr int NCX = W0 + 1;
  constexpr int GX = HW0 / 256;
  int px = (s % GX) * 256 + (int)threadIdx.x;
  int b = (s / GX) % B;
  int dir = s / (GX * B);
  int nb = dir * B + b;
  float fx = flowB[((size_t)(nb * 2 + 0)) * HW0 + px];
  float fy = flowB[((size_t)(nb * 2 + 1)) * HW0 + px];
  int sw = px % W0, sh = px / W0;
  float tx = (float)sw + fx, ty = (float)sh + fy;
  float x0f = floorf(tx), y0f = floorf(ty);
  int x0 = (int)x0f, y0 = (int)y0f;
  if (x0 < -1 || x0 > W0 - 1 || y0 < -1 || y0 > H0 - 1) return;
  const float* imp = (dir ? img1 : img0) + (size_t)b * 3 * HW0;
  float m = msum[b] * invCnt;
  float im0 = imp[px] - m, im1 = imp[(size_t)HW0 + px] - m, im2 = imp[(size_t)2 * HW0 + px] - m;
  const float* sig = dir ? s10 : s01;
  float sg = sig[(size_t)b * HW0 + px];
  union { floatx4 f4[RS_F / 4]; unsigned u[RS_F]; } r;
  r.u[0] = f2h(im0, im1);
  r.u[1] = f2h(im2, sg);
  const floatx4* fp = (const floatx4*)(featN + ((size_t)nb * HW0 + px) * 32);
  union { floatx4 f; unsigned u[4]; } t;
#pragma unroll
  for (int j = 0; j < 4; j++) {
    t.f = fp[j];
    r.u[2 + 4 * j + 0] = t.u[0]; r.u[2 + 4 * j + 1] = t.u[1];
    r.u[2 + 4 * j + 2] = t.u[2]; r.u[2 + 4 * j + 3] = t.u[3];
  }
  r.u[18] = __float_as_uint(tx - x0f);
  r.u[19] = __float_as_uint(ty - y0f);
  unsigned slot = atomicAdd(&curs[nb * NC_F + (y0 + 1) * NCX + (x0 + 1)], 1u);
  floatx4* o = (floatx4*)(recs + (size_t)slot * RS_F);
#pragma unroll
  for (int j = 0; j < RS_F / 4; j++) o[j] = r.f4[j];
}

template <int C, int Hd, int Wd, int RS>
__device__ __forceinline__ void pack_feat_body(
    const _Float16* __restrict__ featN, const float* __restrict__ flowB,
    float* __restrict__ recs, unsigned* __restrict__ curs, int s) {
  constexpr int HWd = Hd * Wd;
  constexpr int NCX = Wd + 1;
  constexpr int NC  = (Wd + 1) * (Hd + 1);
  constexpr int GX = HWd / 256;
  int px = (s % GX) * 256 + (int)threadIdx.x;
  int b = (s / GX) % B;
  int dir = s / (GX * B);
  int nb = dir * B + b;
  float fx = flowB[((size_t)(nb * 2 + 0)) * HWd + px];
  float fy = flowB[((size_t)(nb * 2 + 1)) * HWd + px];
  int sw = px % Wd, sh = px / Wd;
  float tx = (float)sw + fx, ty = (float)sh + fy;
  float x0f = floorf(tx), y0f = floorf(ty);
  int x0 = (int)x0f, y0 = (int)y0f;
  if (x0 < -1 || x0 > Wd - 1 || y0 < -1 || y0 > Hd - 1) return;
  union { floatx4 f4[RS / 4]; unsigned u[RS]; } r;
  const floatx4* fp = (const floatx4*)(featN + ((size_t)nb * HWd + px) * C);
#pragma unroll
  for (int j = 0; j < C / 8; j++) r.f4[j] = fp[j];
  r.u[C / 2]     = __float_as_uint(tx - x0f);
  r.u[C / 2 + 1] = __float_as_uint(ty - y0f);
#pragma unroll
  for (int j = C / 2 + 2; j < RS; j++) r.u[j] = 0;
  unsigned slot = atomicAdd(&curs[nb * NC + (y0 + 1) * NCX + (x0 + 1)], 1u);
  floatx4* o = (floatx4*)(recs + (size_t)slot * RS);
#pragma unroll
  for (int j = 0; j < RS / 4; j++) o[j] = r.f4[j];
}

// ---- gathers: packed-f16 accumulation, merged row-ranges (2 cs loads/pixel-row) ----

__device__ __forceinline__ void gather_full_body(
    const float* __restrict__ recs, const uint2* __restrict__ cs,
    float* __restrict__ outImg, float* __restrict__ outFeat,
    float* __restrict__ outSig, int lb) {
  constexpr int NCX = W0 + 1;
  constexpr int GX = HW0 / 256;
  constexpr int T = GX * B * 2;
  lb = (lb & 7) * (T >> 3) + (lb >> 3);
  int q = (lb % GX) * 256 + (int)threadIdx.x;
  int b = (lb / GX) % B;
  int dir = lb / (GX * B);
  int nb = dir * B + b;
  int qx = q % W0, qy = q / W0;
  half2v ha[18];
#pragma unroll
  for (int j = 0; j < 18; j++) ha[j] = half2v{(_Float16)0.f, (_Float16)0.f};
  float dsum = 0.f;
  for (int ky = 0; ky < 2; ky++) {
    int cy = qy - 1 + ky;
    int base = nb * NC_F + (cy + 1) * NCX + qx;     // left cell (cx=qx-1)
    uint2 scL = cs[base];
    uint2 scR = cs[base + 1];
    unsigned s0 = scL.x, sb = scR.x, sE = scR.x + scR.y;   // contiguous by scan
    for (unsigned s = s0; s < sE; s++) {
      const floatx4* r4 = (const floatx4*)(recs + (size_t)s * RS_F);
      union { floatx4 f; half2v h[4]; } t0, t1, t2, t3, t4;
      t0.f = r4[0]; t1.f = r4[1]; t2.f = r4[2]; t3.f = r4[3]; t4.f = r4[4];
      float dxf = t4.f[2], dyf = t4.f[3];
      float wx = (s < sb) ? dxf : (1.f - dxf);
      float wy = ky ? (1.f - dyf) : dyf;
      float w = wx * wy;
      dsum += w;
      _Float16 wh = (_Float16)w;
      half2v ww = {wh, wh};
#pragma unroll
      for (int j = 0; j < 4; j++) ha[j]      += t0.h[j] * ww;
#pragma unroll
      for (int j = 0; j < 4; j++) ha[4 + j]  += t1.h[j] * ww;
#pragma unroll
      for (int j = 0; j < 4; j++) ha[8 + j]  += t2.h[j] * ww;
#pragma unroll
      for (int j = 0; j < 4; j++) ha[12 + j] += t3.h[j] * ww;
      ha[16] += t4.h[0] * ww;
      ha[17] += t4.h[1] * ww;
    }
  }
  float inv = 1.f / fmaxf(dsum, 1e-7f);
  outImg[((size_t)(b * 6 + dir * 3 + 0)) * HW0 + q] = (float)ha[0][0] * inv;
  outImg[((size_t)(b * 6 + dir * 3 + 1)) * HW0 + q] = (float)ha[0][1] * inv;
  outImg[((size_t)(b * 6 + dir * 3 + 2)) * HW0 + q] = (float)ha[1][0] * inv;
  outSig[((size_t)(b * 2 + dir)) * HW0 + q]         = (float)ha[1][1] * inv;
#pragma unroll
  for (int j = 0; j < 16; j++) {
    outFeat[((size_t)(b * 64 + dir * 32 + 2 * j + 0)) * HW0 + q] = (float)ha[2 + j][0] * inv;
    outFeat[((size_t)(b * 64 + dir * 32 + 2 * j + 1)) * HW0 + q] = (float)ha[2 + j][1] * inv;
  }
}

template <int C, int Hd, int Wd, int RS, int Z>
__device__ __forceinline__ void gather_feat_body(
    const float* __restrict__ recs, const uint2* __restrict__ cs,
    float* __restrict__ outF, int lb) {
  constexpr int HWd = Hd * Wd;
  constexpr int NCX = Wd + 1;
  constexpr int NC  = (Wd + 1) * (Hd + 1);
  constexpr int GX = HWd / 256;
  constexpr int T = GX * B * 2 * Z;
  lb = (lb & 7) * (T >> 3) + (lb >> 3);
  int q = (lb % GX) * 256 + (int)threadIdx.x;
  int b = (lb / GX) % B;
  int dz = lb / (GX * B);
  int z = dz % Z, dir = dz / Z;
  int c0 = z * 32;
  int nb = dir * B + b;
  int qx = q % Wd, qy = q / Wd;
  half2v ha[16];
#pragma unroll
  for (int j = 0; j < 16; j++) ha[j] = half2v{(_Float16)0.f, (_Float16)0.f};
  float dsum = 0.f;
  for (int ky = 0; ky < 2; ky++) {
    int cy = qy - 1 + ky;
    int base = nb * NC + (cy + 1) * NCX + qx;
    uint2 scL = cs[base];
    uint2 scR = cs[base + 1];
    unsigned s0 = scL.x, sb = scR.x, sE = scR.x + scR.y;
    for (unsigned s = s0; s < sE; s++) {
      const float* rp = recs + (size_t)s * RS;
      const floatx4* r4 = (const floatx4*)rp;
      union { floatx4 f; half2v h[4]; } t0, t1, t2, t3;
      t0.f = r4[4 * z + 0]; t1.f = r4[4 * z + 1];
      t2.f = r4[4 * z + 2]; t3.f = r4[4 * z + 3];
      float2 hd = *(const float2*)(rp + C / 2);
      float wx = (s < sb) ? hd.x : (1.f - hd.x);
      float wy = ky ? (1.f - hd.y) : hd.y;
      float w = wx * wy;
      dsum += w;
      _Float16 wh = (_Float16)w;
      half2v ww = {wh, wh};
#pragma unroll
      for (int j = 0; j < 4; j++) ha[j]      += t0.h[j] * ww;
#pragma unroll
      for (int j = 0; j < 4; j++) ha[4 + j]  += t1.h[j] * ww;
#pragma unroll
      for (int j = 0; j < 4; j++) ha[8 + j]  += t2.h[j] * ww;
#pragma unroll
      for (int j = 0; j < 4; j++) ha[12 + j] += t3.h[j] * ww;
    }
  }
  float inv = 1.f / fmaxf(dsum, 1e-7f);
  size_t obase = ((size_t)(b * 2 * C + dir * C + c0)) * HWd + q;
#pragma unroll
  for (int j = 0; j < 16; j++) {
    outF[obase + (size_t)(2 * j + 0) * HWd] = (float)ha[j][0] * inv;
    outF[obase + (size_t)(2 * j + 1) * HWd] = (float)ha[j][1] * inv;
  }
}

// ================= merged kernels =================

__global__ __launch_bounds__(256) void k_front(
    const float* f01, const float* s01, const float* f10, const float* s10,
    float* flowF, unsigned* cntF,
    const float* img0, const float* img1, float* msum,
    const float* w2, const float* w3, const float* w4, const float* w5, const float* w6,
    _Float16* o2, _Float16* o3, _Float16* o4, _Float16* o5, _Float16* o6) {
  int f = blockIdx.x;
  if (f < NB_IF) d_interflow2(f01, s01, f10, s10, flowF, cntF, f);
  else if (f < NB_IF + NB_MEAN) d_mean(img0, img1, msum, f - NB_IF);
  else d_wtrans(w2, w3, w4, w5, w6, o2, o3, o4, o5, o6, f - NB_IF - NB_MEAN);
}

__global__ __launch_bounds__(256) void k_down_conv1(
    const float* flowF, float* flowH, unsigned* cntH, float* flowQ, unsigned* cntQ,
    const float* img0, const float* img1, const float* msum, float invCnt,
    const float* w1, const float* b1, const float* a1, _Float16* Ah) {
  int f = blockIdx.x;
  if (f < NB_DH) d_downflow2<2, H1, W1>(flowF, flowH, cntH, f);
  else if (f < NB_DH + NB_DQ) d_downflow2<4, H2, W2>(flowF, flowQ, cntQ, f - NB_DH);
  else d_conv1(img0, img1, msum, invCnt, w1, b1, a1, Ah, f - NB_DH - NB_DQ);
}

__global__ __launch_bounds__(256) void k_scan_conv2(
    const unsigned* cntAll, unsigned* tpre, unsigned* psum,
    const _Float16* Ah, const _Float16* wt2, const float* b2, const float* a2,
    _Float16* Bh) {
  int f = blockIdx.x;
  if (f < NCHUNKS) d_scan_part(cntAll, tpre, psum, f);
  else conv_mfma_body<32, 32, 1, 8>(Ah, wt2, b2, a2, Bh, H0, W0, H0, W0,
                                    224, 1, 8, f - NCHUNKS);
}

__global__ __launch_bounds__(256) void k_scan_apply(
    const unsigned* __restrict__ cnt, const unsigned* __restrict__ tpre,
    const unsigned* __restrict__ psum,
    uint2* __restrict__ cs, unsigned* __restrict__ curs) {
  int b = blockIdx.x, t = threadIdx.x;
  int off, sz, ci;
  chunk_map(b, off, sz, ci);
  __shared__ unsigned cbs;
  if (t == 0) {
    int first = (off == 0) ? 0 : (off == SZ_F ? NCH_F : NCH_F + NCH_H);
    unsigned c = 0;
    for (int k = first; k < first + ci; k++) c += psum[k];
    cbs = c;
  }
  __syncthreads();
  int base = off + ci * CHUNK + t * 64;
  int lim = off + min(sz, (ci + 1) * CHUNK);
  unsigned run = cbs + tpre[b * 256 + t];
  for (int j = 0; j < 64; j++) {
    int idx = base + j;
    if (idx < lim) {
      unsigned c = cnt[idx];
      cs[idx] = make_uint2(run, c);
      curs[idx] = run;
      run += c;
    }
  }
}

__global__ __launch_bounds__(256) void k_packF_conv3(
    const float* img0, const float* img1, const float* msum, float invCnt,
    const _Float16* Bh, const float* s01, const float* s10, const float* flowF,
    float* recs, unsigned* cursF,
    const _Float16* wt3, const float* b3, const float* a3, _Float16* Ah) {
  int f = blockIdx.x;
  if (f < NB_PF)
    pack_full_body(img0, img1, msum, invCnt, Bh, s01, s10, flowF, recs, cursF, f);
  else
    conv_mfma_body<32, 64, 2, 4>(Bh, wt3, b3, a3, Ah, H0, W0, H1, W1,
                                 112, 2, 8, f - NB_PF);
}

__global__ __launch_bounds__(256) void k_gatherF_conv4(
    const float* recs, const uint2* csF,
    float* outImg, float* outFeat, float* outSig,
    const _Float16* Ah, const _Float16* wt4, const float* b4, const float* a4,
    _Float16* Bh) {
  int f = blockIdx.x;
  if (f < NB_GF)
    gather_full_body(recs, csF, outImg, outFeat, outSig, f);
  else
    conv_mfma_body<64, 64, 1, 8>(Ah, wt4, b4, a4, Bh, H1, W1, H1, W1,
                                 56, 2, 8, f - NB_GF);
}

__global__ __launch_bounds__(256) void k_packH_conv5(
    const _Float16* Bh, const float* flowH, float* recs, unsigned* cursH,
    const _Float16* wt5, const float* b5, const float* a5, _Float16* Ah) {
  int f = blockIdx.x;
  if (f < NB_PH)
    pack_feat_body<64, H1, W1, RS_H>(Bh, flowH, recs, cursH, f);
  else
    conv_mfma_body<64, 96, 2, 4>(Bh, wt5, b5, a5, Ah, H1, W1, H2, W2,
                                 28, 3, 8, f - NB_PH);
}

__global__ __launch_bounds__(256) void k_gatherH_conv6(
    const float* recs, const uint2* csH, float* outF2,
    const _Float16* Ah, const _Float16* wt6, const float* b6, const float* a6,
    _Float16* Bh) {
  int f = blockIdx.x;
  if (f < NB_GH)
    gather_feat_body<64, H1, W1, RS_H, 2>(recs, csH, outF2, f);
  else
    conv_mfma_body<96, 96, 1, 4>(Ah, wt6, b6, a6, Bh, H2, W2, H2, W2,
                                 28, 3, 8, f - NB_GH);
}

__global__ __launch_bounds__(256) void k_packQ(
    const _Float16* Bh, const float* flowQ, float* recs, unsigned* cursQ) {
  pack_feat_body<96, H2, W2, RS_Q>(Bh, flowQ, recs, cursQ, blockIdx.x);
}

__global__ __launch_bounds__(256) void k_gatherQ(
    const float* recs, const uint2* csQ, float* outF3) {
  gather_feat_body<96, H2, W2, RS_Q, 3>(recs, csQ, outF3, blockIdx.x);
}

extern "C" void kernel_launch(void* const* d_in, const int* in_sizes, int n_in,
                              void* d_out, int out_size, void* d_ws, size_t ws_size,
                              hipStream_t stream) {
  (void)in_sizes; (void)n_in; (void)out_size;
  if (ws_size < WS_FLOATS * sizeof(float)) return;

  const float* img0    = (const float*)d_in[0];
  const float* img1    = (const float*)d_in[1];
  const float* flow01  = (const float*)d_in[2];
  const float* sigma01 = (const float*)d_in[3];
  const float* flow10  = (const float*)d_in[4];
  const float* sigma10 = (const float*)d_in[5];
  const float* wp[6]; const float* bp[6]; const float* ap[6];
  for (int i = 0; i < 6; i++) {
    wp[i] = (const float*)(d_in[6 + 3 * i]);
    bp[i] = (const float*)(d_in[7 + 3 * i]);
    ap[i] = (const float*)(d_in[8 + 3 * i]);
  }
  float* ws  = (float*)d_ws;
  float* out = (float*)d_out;

  unsigned* cntAll  = (unsigned*)(ws + OFF_CNT);
  unsigned* cntF = cntAll;
  unsigned* cntH = cntAll + SZ_F;
  unsigned* cntQ = cntAll + SZ_F + SZ_H;
  uint2*    csAll = (uint2*)(ws + OFF_CS);
  uint2*    csF = csAll, *csH = csAll + SZ_F, *csQ = csAll + SZ_F + SZ_H;
  unsigned* cursAll  = (unsigned*)(ws + OFF_CURS);
  unsigned* cursF = cursAll, *cursH = cursAll + SZ_F, *cursQ = cursAll + SZ_F + SZ_H;
  unsigned* tpre  = (unsigned*)(ws + OFF_TPRE);
  unsigned* psum  = (unsigned*)(ws + OFF_PSUM);
  float*    recs  = ws + OFF_RECS;
  _Float16* Ah = (_Float16*)(ws + OFF_BUFA);
  _Float16* Bh = (_Float16*)(ws + OFF_BUFB);
  _Float16* wt[5] = {(_Float16*)(ws + OFF_WT2), (_Float16*)(ws + OFF_WT3),
                     (_Float16*)(ws + OFF_WT4), (_Float16*)(ws + OFF_WT5),
                     (_Float16*)(ws + OFF_WT6)};
  float* flowF = ws + OFF_FLOW;
  float* flowH = ws + OFF_FLH;
  float* flowQ = ws + OFF_FLQ;

  const float invCnt = 1.f / (6.f * (float)HW0);

  dim3 blk(256);

  // 0: fast zero of mean + cnt regions
  k_zero<<<dim3(1024), blk, 0, stream>>>((floatx4*)ws, (int)(ZERO_FLOATS / 4));

  // 1: interflow || mean || wtrans
  k_front<<<dim3(NB_IF + NB_MEAN + NB_WT), blk, 0, stream>>>(
      flow01, sigma01, flow10, sigma10, flowF, cntF,
      img0, img1, ws + OFF_MEAN,
      wp[1], wp[2], wp[3], wp[4], wp[5], wt[0], wt[1], wt[2], wt[3], wt[4]);

  // 2: downflowH || downflowQ || conv1
  k_down_conv1<<<dim3(NB_DH + NB_DQ + NB_C1), blk, 0, stream>>>(
      flowF, flowH, cntH, flowQ, cntQ,
      img0, img1, ws + OFF_MEAN, invCnt, wp[0], bp[0], ap[0], Ah);

  // 3: scan_part || conv2
  k_scan_conv2<<<dim3(NCHUNKS + NB_C2), blk, 0, stream>>>(
      cntAll, tpre, psum, Ah, wt[0], bp[1], ap[1], Bh);

  // 4: scan_apply
  k_scan_apply<<<dim3(NCHUNKS), blk, 0, stream>>>(cntAll, tpre, psum, csAll, cursAll);

  // 5: pack_full || conv3
  k_packF_conv3<<<dim3(NB_PF + NB_C3), blk, 0, stream>>>(
      img0, img1, ws + OFF_MEAN, invCnt, Bh, sigma01, sigma10, flowF,
      recs, cursF, wt[1], bp[2], ap[2], Ah);

  // 6: gather_full || conv4
  k_gatherF_conv4<<<dim3(NB_GF + NB_C4), blk, 0, stream>>>(
      recs, csF, out + O_IMG, out + O_F1, out + O_SIG,
      Ah, wt[2], bp[3], ap[3], Bh);

  // 7: pack_H || conv5
  k_packH_conv5<<<dim3(NB_PH + NB_C5), blk, 0, stream>>>(
      Bh, flowH, recs, cursH, wt[3], bp[4], ap[4], Ah);

  // 8: gather_H || conv6
  k_gatherH_conv6<<<dim3(NB_GH + NB_C6), blk, 0, stream>>>(
      recs, csH, out + O_F2, Ah, wt[4], bp[5], ap[5], Bh);

  // 9: pack_Q ; 10: gather_Q
  k_packQ<<<dim3((HW2 / 256) * B * 2), blk, 0, stream>>>(Bh, flowQ, recs, cursQ);
  k_gatherQ<<<dim3((HW2 / 256) * B * 6), blk, 0, stream>>>(recs, csQ, out + O_F3);
}

// Round 18
// 553.474 us; speedup vs baseline: 1.1803x; 1.0123x over previous
//
#include <hip/hip_runtime.h>
#include <hip/hip_fp16.h>

static constexpr int B  = 4;
static constexpr int H0 = 256, W0 = 448, HW0 = H0 * W0;   // full
static constexpr int H1 = 128, W1 = 224, HW1 = H1 * W1;   // half
static constexpr int H2 = 64,  W2 = 112, HW2 = H2 * W2;   // quarter

typedef _Float16 half8_t __attribute__((ext_vector_type(8)));
typedef _Float16 half4_t __attribute__((ext_vector_type(4)));
typedef _Float16 half2v  __attribute__((ext_vector_type(2)));
typedef float floatx4 __attribute__((ext_vector_type(4)));

static constexpr int NC_F = (W0 + 1) * (H0 + 1);
static constexpr int NC_H = (W1 + 1) * (H1 + 1);
static constexpr int NC_Q = (W2 + 1) * (H2 + 1);

static constexpr int RS_F = 20;
static constexpr int RS_H = 36;
static constexpr int RS_Q = 52;

static constexpr int SZ_F = 2 * B * NC_F;
static constexpr int SZ_H = 2 * B * NC_H;
static constexpr int SZ_Q = 2 * B * NC_Q;
static constexpr int CNT_TOTAL = SZ_F + SZ_H + SZ_Q;

static constexpr int CHUNK = 16384;
static constexpr int NCH_F = (SZ_F + CHUNK - 1) / CHUNK;
static constexpr int NCH_H = (SZ_H + CHUNK - 1) / CHUNK;
static constexpr int NCH_Q = (SZ_Q + CHUNK - 1) / CHUNK;
static constexpr int NCHUNKS = NCH_F + NCH_H + NCH_Q;     // 76

// ---------------- workspace layout (floats) ----------------
static constexpr size_t OFF_MEAN   = 0;
static constexpr size_t OFF_CNT    = 256;
static constexpr size_t ZERO_FLOATS = OFF_CNT + CNT_TOTAL;   // divisible by 4
static constexpr size_t OFF_BUFA   = ZERO_FLOATS;
static constexpr size_t OFF_BUFB   = OFF_BUFA + (size_t)4 * 32 * HW0;
static constexpr size_t OFF_FLOW   = OFF_BUFB + (size_t)4 * 32 * HW0;
static constexpr size_t OFF_FLH    = OFF_FLOW + (size_t)2 * B * 2 * HW0;
static constexpr size_t OFF_FLQ    = OFF_FLH + (size_t)2 * B * 2 * HW1;
static constexpr size_t OFF_WT2 = OFF_FLQ + (size_t)2 * B * 2 * HW2;
static constexpr size_t OFF_WT3 = OFF_WT2 + 4608;
static constexpr size_t OFF_WT4 = OFF_WT3 + 9216;
static constexpr size_t OFF_WT5 = OFF_WT4 + 18432;
static constexpr size_t OFF_WT6 = OFF_WT5 + 27648;
static constexpr size_t OFF_CS   = OFF_WT6 + 41472;
static constexpr size_t OFF_CURS = OFF_CS + (size_t)2 * CNT_TOTAL;
static constexpr size_t OFF_TPRE = OFF_CURS + CNT_TOTAL;
static constexpr size_t OFF_PSUM = OFF_TPRE + (size_t)NCHUNKS * 256;
static constexpr size_t OFF_RECS = OFF_PSUM + 128;
static constexpr size_t WS_FLOATS = OFF_RECS + (size_t)2 * B * HW0 * RS_F;

// ---------------- output layout (floats) ----------------
static constexpr size_t O_IMG = 0;
static constexpr size_t O_F1  = O_IMG + (size_t)B * 6 * HW0;
static constexpr size_t O_F2  = O_F1  + (size_t)B * 64 * HW0;
static constexpr size_t O_F3  = O_F2  + (size_t)B * 128 * HW1;
static constexpr size_t O_SIG = O_F3  + (size_t)B * 192 * HW2;

// sub-grid block counts (all multiples of 8 -> bijective XCD swizzle)
static constexpr int NB_IF = 2 * B * HW0 / 256;   // 3584
static constexpr int NB_MEAN = 32 * B;            // 128
static constexpr int NB_WT = (202752 + 255) / 256;// 792
static constexpr int NB_DH = 2 * B * HW1 / 256;   // 896
static constexpr int NB_DQ = 2 * B * HW2 / 256;   // 224
static constexpr int NB_C1 = 448 * 8;             // 3584
static constexpr int NB_C2 = 224 * 8;             // 1792
static constexpr int NB_PF = (HW0 / 256) * B * 2; // 3584
static constexpr int NB_C3 = 112 * 2 * 8;         // 1792
static constexpr int NB_GF = NB_PF;               // 3584
static constexpr int NB_C4 = 56 * 2 * 8;          // 896
static constexpr int NB_PH = (HW1 / 256) * B * 2; // 896
static constexpr int NB_C5 = 28 * 3 * 8;          // 672
static constexpr int NB_GH = (HW1 / 256) * B * 4; // 1792 (Z=2 x 2 dirs)
static constexpr int NB_C6 = 28 * 3 * 8;          // 672

__device__ inline unsigned f2h(float lo, float hi) {
  __half2 h = __floats2half2_rn(lo, hi);
  return *reinterpret_cast<unsigned*>(&h);
}

__device__ inline void chunk_map(int b, int& off, int& sz, int& ci) {
  if (b < NCH_F)              { off = 0;           sz = SZ_F; ci = b; }
  else if (b < NCH_F + NCH_H) { off = SZ_F;        sz = SZ_H; ci = b - NCH_F; }
  else                        { off = SZ_F + SZ_H; sz = SZ_Q; ci = b - NCH_F - NCH_H; }
}

// ---------------- fast zero ----------------
__global__ __launch_bounds__(256) void k_zero(floatx4* __restrict__ p, int n4) {
  floatx4 z = {};
  for (int i = blockIdx.x * 256 + threadIdx.x; i < n4; i += gridDim.x * 256)
    p[i] = z;
}

// ================= device bodies =================

__device__ __forceinline__ void d_mean(const float* __restrict__ img0,
                                       const float* __restrict__ img1,
                                       float* __restrict__ msum, int s) {
  const int perImg = 3 * HW0;
  int bx = s & 31, b = s >> 5;
  float acc = 0.f;
  int tot = 2 * perImg;
  for (int i = bx * 256 + threadIdx.x; i < tot; i += 32 * 256) {
    acc += (i < perImg) ? img0[(size_t)b * perImg + i] : img1[(size_t)b * perImg + (i - perImg)];
  }
#pragma unroll
  for (int o = 32; o > 0; o >>= 1) acc += __shfl_down(acc, o);
  __shared__ float red[4];
  int lane = threadIdx.x & 63, wid = threadIdx.x >> 6;
  if (lane == 0) red[wid] = acc;
  __syncthreads();
  if (threadIdx.x == 0) atomicAdd(&msum[b], red[0] + red[1] + red[2] + red[3]);
}

__device__ __forceinline__ void d_interflow2(
    const float* __restrict__ f01, const float* __restrict__ s01,
    const float* __restrict__ f10, const float* __restrict__ s10,
    float* __restrict__ outBase, unsigned* __restrict__ cntF, int s) {
  constexpr int NCX = W0 + 1;
  int i = s * 256 + (int)threadIdx.x;
  if (i >= 2 * B * HW0) return;
  int nb = i / HW0;
  int px = i - nb * HW0;
  int dir = nb >> 2, b = nb & 3;
  const float* flo = dir ? f10 : f01;
  const float* sigma = dir ? s10 : s01;
  float fx = flo[((size_t)(b * 2 + 0)) * HW0 + px];
  float fy = flo[((size_t)(b * 2 + 1)) * HW0 + px];
  float sg = sigma[(size_t)b * HW0 + px];
  float ftx, fty;
  if (fabsf(sg) < 0.01f) {
    ftx = 0.5f * fx; fty = 0.5f * fy;
  } else {
    float g = (1.f - sqrtf(fmaxf(0.f, 1.f - sg * sg))) / (2.f * sg);
    ftx = 0.5f * fx - g * fy;
    fty = 0.5f * fy + g * fx;
  }
  outBase[((size_t)(nb * 2 + 0)) * HW0 + px] = ftx;
  outBase[((size_t)(nb * 2 + 1)) * HW0 + px] = fty;
  int sw = px % W0, sh = px / W0;
  float tx = (float)sw + ftx, ty = (float)sh + fty;
  int x0 = (int)floorf(tx), y0 = (int)floorf(ty);
  if (x0 >= -1 && x0 <= W0 - 1 && y0 >= -1 && y0 <= H0 - 1)
    atomicAdd(&cntF[nb * NC_F + (y0 + 1) * NCX + (x0 + 1)], 1u);
}

template <int F, int Hd, int Wd>
__device__ __forceinline__ void d_downflow2(
    const float* __restrict__ in, float* __restrict__ out,
    unsigned* __restrict__ cnt, int s) {
  constexpr int HWd = Hd * Wd;
  constexpr int NCX = Wd + 1;
  constexpr int NC  = (Wd + 1) * (Hd + 1);
  int i = s * 256 + (int)threadIdx.x;
  if (i >= 2 * B * HWd) return;
  int nb = i / HWd;
  int px = i - nb * HWd;
  int ow = px % Wd, oh = px / Wd;
  float cy = (oh + 0.5f) * F - 0.5f;
  float cx = (ow + 0.5f) * F - 0.5f;
  int ylo = (int)floorf(cy) - F + 1;
  int xlo = (int)floorf(cx) - F + 1;
  const float* ipx = in + ((size_t)(nb * 2 + 0)) * HW0;
  const float* ipy = in + ((size_t)(nb * 2 + 1)) * HW0;
  float ax = 0.f, ay = 0.f, wn = 0.f;
  for (int jy = 0; jy < 2 * F; jy++) {
    int y = ylo + jy;
    if ((unsigned)y >= (unsigned)H0) continue;
    float wy = 1.f - fabsf((float)y - cy) / (float)F;
    for (int jx = 0; jx < 2 * F; jx++) {
      int x = xlo + jx;
      if ((unsigned)x >= (unsigned)W0) continue;
      float wx = 1.f - fabsf((float)x - cx) / (float)F;
      float ww = wy * wx;
      ax += ww * ipx[(size_t)y * W0 + x];
      ay += ww * ipy[(size_t)y * W0 + x];
      wn += ww;
    }
  }
  float sc = 1.f / (wn * (float)F);
  float fx = ax * sc, fy = ay * sc;
  out[((size_t)(nb * 2 + 0)) * HWd + px] = fx;
  out[((size_t)(nb * 2 + 1)) * HWd + px] = fy;
  float tx = (float)ow + fx, ty = (float)oh + fy;
  int x0 = (int)floorf(tx), y0 = (int)floorf(ty);
  if (x0 >= -1 && x0 <= Wd - 1 && y0 >= -1 && y0 <= Hd - 1)
    atomicAdd(&cnt[nb * NC + (y0 + 1) * NCX + (x0 + 1)], 1u);
}

__device__ __forceinline__ void d_wtrans(
    const float* __restrict__ w2, const float* __restrict__ w3,
    const float* __restrict__ w4, const float* __restrict__ w5,
    const float* __restrict__ w6,
    _Float16* __restrict__ o2, _Float16* __restrict__ o3,
    _Float16* __restrict__ o4, _Float16* __restrict__ o5,
    _Float16* __restrict__ o6, int s) {
  int i = s * 256 + (int)threadIdx.x;
  const float* w; _Float16* o; int COUT, CIN, base;
  if      (i <   9216) { w = w2; o = o2; COUT = 32; CIN = 32; base = 0; }
  else if (i <  27648) { w = w3; o = o3; COUT = 64; CIN = 32; base = 9216; }
  else if (i <  64512) { w = w4; o = o4; COUT = 64; CIN = 64; base = 27648; }
  else if (i < 119808) { w = w5; o = o5; COUT = 96; CIN = 64; base = 64512; }
  else if (i < 202752) { w = w6; o = o6; COUT = 96; CIN = 96; base = 119808; }
  else return;
  int j = i - base;
  int q = j % 9;
  int rest = j / 9;
  int ci = rest % CIN;
  int co = rest / CIN;
  o[((size_t)q * COUT + co) * CIN + ci] = (_Float16)w[j];
}

__device__ __forceinline__ void d_conv1(
    const float* __restrict__ img0, const float* __restrict__ img1,
    const float* __restrict__ msum, float invCnt,
    const float* __restrict__ wgt, const float* __restrict__ bias,
    const float* __restrict__ alpha, _Float16* __restrict__ outp, int s) {
  __shared__ float wsm[32 * 27];
  __shared__ float bsm[32];
  int bx = s % 448, n = s / 448;
  for (int i = threadIdx.x; i < 32 * 27; i += 256) wsm[i] = wgt[i];
  if (threadIdx.x < 32) bsm[threadIdx.x] = bias[threadIdx.x];
  __syncthreads();
  int b = n & 3;
  const float* ip = (n < 4 ? img0 : img1) + (size_t)b * 3 * HW0;
  float m = msum[b] * invCnt;
  int tx = bx % 7, ty = bx / 7;
  int ow = tx * 64 + (threadIdx.x & 63);
  int oh = ty * 4 + (threadIdx.x >> 6);
  float xv[27];
#pragma unroll
  for (int ci = 0; ci < 3; ci++) {
    const float* iq = ip + (size_t)ci * HW0;
#pragma unroll
    for (int ky = 0; ky < 3; ky++) {
      int y = oh - 1 + ky;
      bool yv = (unsigned)y < (unsigned)H0;
      const float* row = iq + (size_t)y * W0;
#pragma unroll
      for (int kx = 0; kx < 3; kx++) {
        int x = ow - 1 + kx;
        xv[ci * 9 + ky * 3 + kx] = (yv && (unsigned)x < (unsigned)W0) ? row[x] - m : 0.f;
      }
    }
  }
  float a = alpha[0];
  _Float16* ob = outp + ((size_t)(n * H0 + oh) * W0 + ow) * 32;
#pragma clang loop unroll(disable)
  for (int g = 0; g < 4; g++) {
    float acc[8];
#pragma unroll
    for (int k = 0; k < 8; k++) acc[k] = bsm[g * 8 + k];
#pragma unroll
    for (int k = 0; k < 8; k++) {
      const float* wp = &wsm[(g * 8 + k) * 27];
#pragma unroll
      for (int j = 0; j < 27; j++) acc[k] += xv[j] * wp[j];
    }
    half8_t h;
#pragma unroll
    for (int k = 0; k < 8; k++) {
      float v = acc[k];
      v = v > 0.f ? v : a * v;
      h[k] = (_Float16)v;
    }
    *(half8_t*)(ob + g * 8) = h;
  }
}

template <int CIN, int COUT, int STRIDE, int TROWS>
__device__ __forceinline__ void conv_mfma_body(
    const _Float16* __restrict__ in, const _Float16* __restrict__ wT,
    const float* __restrict__ bias, const float* __restrict__ alpha,
    _Float16* __restrict__ outp, int Hin, int Win, int Hout, int Wout,
    int gx, int gy, int gz, int lb) {
  int T = gx * gy * gz;
  lb = (lb & 7) * (T >> 3) + (lb >> 3);
  int cob  = lb % gy;
  int n    = (lb / gy) % gz;
  int tile = lb / (gy * gz);
  int lane = threadIdx.x & 63, wave = threadIdx.x >> 6;
  int l15 = lane & 15, lhi = lane >> 4;
  int tiles_x = Wout >> 4;
  int tx = tile % tiles_x, ty = tile / tiles_x;
  int ow0 = tx << 4;
  int oh0 = ty * (4 * TROWS) + wave * TROWS;
  int co0 = cob * 32;
  floatx4 acc[2][TROWS] = {};
  const _Float16* ip = in + (size_t)n * Hin * Win * CIN;
  int x_base = (ow0 + l15) * STRIDE;
  int ybase = oh0 * STRIDE - 1;
  constexpr int NY = (TROWS - 1) * STRIDE + 3;
  const _Float16* wA = wT + (size_t)(co0 + l15) * CIN;
  const _Float16* wB = wT + (size_t)(co0 + 16 + l15) * CIN;
  for (int kc = 0; kc < CIN / 32; kc++) {
    int ci = kc * 32 + lhi * 8;
#pragma unroll
    for (int dxi = 0; dxi < 3; dxi++) {
      int x = x_base + dxi - 1;
      bool xv = (unsigned)x < (unsigned)Win;
      int xc = x < 0 ? 0 : (x >= Win ? Win - 1 : x);
      half8_t a0[3], a1[3];
#pragma unroll
      for (int dy = 0; dy < 3; dy++) {
        int q = dy * 3 + dxi;
        a0[dy] = *(const half8_t*)(wA + (size_t)q * COUT * CIN + ci);
        a1[dy] = *(const half8_t*)(wB + (size_t)q * COUT * CIN + ci);
      }
#pragma unroll
      for (int y6 = 0; y6 < NY; y6++) {
        int y = ybase + y6;
        if ((unsigned)y >= (unsigned)Hin) continue;   // wave-uniform; skip == zero-pad
        half8_t bf = *(const half8_t*)(ip + ((size_t)y * Win + xc) * CIN + ci);
        half8_t z = {};
        bf = xv ? bf : z;
#pragma unroll
        for (int dy = 0; dy < 3; dy++) {
          int tnum = y6 - dy;
          if (tnum < 0 || tnum % STRIDE != 0) continue;
          int t = tnum / STRIDE;
          if (t >= TROWS) continue;
          acc[0][t] = __builtin_amdgcn_mfma_f32_16x16x32_f16(a0[dy], bf, acc[0][t], 0, 0, 0);
          acc[1][t] = __builtin_amdgcn_mfma_f32_16x16x32_f16(a1[dy], bf, acc[1][t], 0, 0, 0);
        }
      }
    }
  }
  float aP = alpha[0];
#pragma unroll
  for (int h = 0; h < 2; h++) {
    float bia[4];
#pragma unroll
    for (int r = 0; r < 4; r++) bia[r] = bias[co0 + h * 16 + lhi * 4 + r];
#pragma unroll
    for (int t = 0; t < TROWS; t++) {
      half4_t hh;
#pragma unroll
      for (int r = 0; r < 4; r++) {
        float v = acc[h][t][r] + bia[r];
        v = v > 0.f ? v : aP * v;
        hh[r] = (_Float16)v;
      }
      *(half4_t*)(outp + (((size_t)n * Hout + oh0 + t) * Wout + ow0 + l15) * COUT +
                  co0 + h * 16 + lhi * 4) = hh;
    }
  }
}

__device__ __forceinline__ void d_scan_part(
    const unsigned* __restrict__ cnt, unsigned* __restrict__ tpre,
    unsigned* __restrict__ psum, int b) {
  int t = threadIdx.x;
  int off, sz, ci;
  chunk_map(b, off, sz, ci);
  int base = off + ci * CHUNK + t * 64;
  int lim = off + min(sz, (ci + 1) * CHUNK);
  unsigned s = 0;
  for (int j = 0; j < 64; j++) {
    int idx = base + j;
    if (idx < lim) s += cnt[idx];
  }
  __shared__ unsigned sm[256];
  sm[t] = s;
  __syncthreads();
  for (int o = 1; o < 256; o <<= 1) {
    unsigned v = (t >= o) ? sm[t - o] : 0u;
    __syncthreads();
    sm[t] += v;
    __syncthreads();
  }
  unsigned incl = sm[t];
  tpre[b * 256 + t] = incl - s;
  if (t == 255) psum[b] = incl;
}

__device__ __forceinline__ void pack_full_body(
    const float* __restrict__ img0, const float* __restrict__ img1,
    const float* __restrict__ msum, float invCnt,
    const _Float16* __restrict__ featN,
    const float* __restrict__ s01, const float* __restrict__ s10,
    const float* __restrict__ flowB,
    float* __restrict__ recs, unsigned* __restrict__ curs, int s) {
  constexpr int NCX = W0 + 1;
  constexpr int GX = HW0 / 256;
  int px = (s % GX) * 256 + (int)threadIdx.x;
  int b = (s / GX) % B;
  int dir = s / (GX * B);
  int nb = dir * B + b;
  float fx = flowB[((size_t)(nb * 2 + 0)) * HW0 + px];
  float fy = flowB[((size_t)(nb * 2 + 1)) * HW0 + px];
  int sw = px % W0, sh = px / W0;
  float tx = (float)sw + fx, ty = (float)sh + fy;
  float x0f = floorf(tx), y0f = floorf(ty);
  int x0 = (int)x0f, y0 = (int)y0f;
  if (x0 < -1 || x0 > W0 - 1 || y0 < -1 || y0 > H0 - 1) return;
  const float* imp = (dir ? img1 : img0) + (size_t)b * 3 * HW0;
  float m = msum[b] * invCnt;
  float im0 = imp[px] - m, im1 = imp[(size_t)HW0 + px] - m, im2 = imp[(size_t)2 * HW0 + px] - m;
  const float* sig = dir ? s10 : s01;
  float sg = sig[(size_t)b * HW0 + px];
  union { floatx4 f4[RS_F / 4]; unsigned u[RS_F]; } r;
  r.u[0] = f2h(im0, im1);
  r.u[1] = f2h(im2, sg);
  const floatx4* fp = (const floatx4*)(featN + ((size_t)nb * HW0 + px) * 32);
  union { floatx4 f; unsigned u[4]; } t;
#pragma unroll
  for (int j = 0; j < 4; j++) {
    t.f = fp[j];
    r.u[2 + 4 * j + 0] = t.u[0]; r.u[2 + 4 * j + 1] = t.u[1];
    r.u[2 + 4 * j + 2] = t.u[2]; r.u[2 + 4 * j + 3] = t.u[3];
  }
  r.u[18] = __float_as_uint(tx - x0f);
  r.u[19] = __float_as_uint(ty - y0f);
  unsigned slot = atomicAdd(&curs[nb * NC_F + (y0 + 1) * NCX + (x0 + 1)], 1u);
  floatx4* o = (floatx4*)(recs + (size_t)slot * RS_F);
#pragma unroll
  for (int j = 0; j < RS_F / 4; j++) o[j] = r.f4[j];
}

template <int C, int Hd, int Wd, int RS>
__device__ __forceinline__ void pack_feat_body(
    const _Float16* __restrict__ featN, const float* __restrict__ flowB,
    float* __restrict__ recs, unsigned* __restrict__ curs, int s) {
  constexpr int HWd = Hd * Wd;
  constexpr int NCX = Wd + 1;
  constexpr int NC  = (Wd + 1) * (Hd + 1);
  constexpr int GX = HWd / 256;
  int px = (s % GX) * 256 + (int)threadIdx.x;
  int b = (s / GX) % B;
  int dir = s / (GX * B);
  int nb = dir * B + b;
  float fx = flowB[((size_t)(nb * 2 + 0)) * HWd + px];
  float fy = flowB[((size_t)(nb * 2 + 1)) * HWd + px];
  int sw = px % Wd, sh = px / Wd;
  float tx = (float)sw + fx, ty = (float)sh + fy;
  float x0f = floorf(tx), y0f = floorf(ty);
  int x0 = (int)x0f, y0 = (int)y0f;
  if (x0 < -1 || x0 > Wd - 1 || y0 < -1 || y0 > Hd - 1) return;
  union { floatx4 f4[RS / 4]; unsigned u[RS]; } r;
  const floatx4* fp = (const floatx4*)(featN + ((size_t)nb * HWd + px) * C);
#pragma unroll
  for (int j = 0; j < C / 8; j++) r.f4[j] = fp[j];
  r.u[C / 2]     = __float_as_uint(tx - x0f);
  r.u[C / 2 + 1] = __float_as_uint(ty - y0f);
#pragma unroll
  for (int j = C / 2 + 2; j < RS; j++) r.u[j] = 0;
  unsigned slot = atomicAdd(&curs[nb * NC + (y0 + 1) * NCX + (x0 + 1)], 1u);
  floatx4* o = (floatx4*)(recs + (size_t)slot * RS);
#pragma unroll
  for (int j = 0; j < RS / 4; j++) o[j] = r.f4[j];
}

// ---- gathers: packed-f16 accumulation, merged row-ranges, natural block order ----

__device__ __forceinline__ void gather_full_body(
    const float* __restrict__ recs, const uint2* __restrict__ cs,
    float* __restrict__ outImg, float* __restrict__ outFeat,
    float* __restrict__ outSig, int lb) {
  constexpr int NCX = W0 + 1;
  constexpr int GX = HW0 / 256;
  // natural order: lb%8 spreads horizontally-adjacent blocks across XCDs
  // (vertical neighbors are GX=448 apart, 448%8==0 -> same XCD: reuse kept)
  int q = (lb % GX) * 256 + (int)threadIdx.x;
  int b = (lb / GX) % B;
  int dir = lb / (GX * B);
  int nb = dir * B + b;
  int qx = q % W0, qy = q / W0;
  half2v ha[18];
#pragma unroll
  for (int j = 0; j < 18; j++) ha[j] = half2v{(_Float16)0.f, (_Float16)0.f};
  float dsum = 0.f;
  for (int ky = 0; ky < 2; ky++) {
    int cy = qy - 1 + ky;
    int base = nb * NC_F + (cy + 1) * NCX + qx;     // left cell (cx=qx-1)
    uint2 scL = cs[base];
    uint2 scR = cs[base + 1];
    unsigned s0 = scL.x, sb = scR.x, sE = scR.x + scR.y;   // contiguous by scan
    for (unsigned s = s0; s < sE; s++) {
      const floatx4* r4 = (const floatx4*)(recs + (size_t)s * RS_F);
      union { floatx4 f; half2v h[4]; } t0, t1, t2, t3, t4;
      t0.f = r4[0]; t1.f = r4[1]; t2.f = r4[2]; t3.f = r4[3]; t4.f = r4[4];
      float dxf = t4.f[2], dyf = t4.f[3];
      float wx = (s < sb) ? dxf : (1.f - dxf);
      float wy = ky ? (1.f - dyf) : dyf;
      float w = wx * wy;
      dsum += w;
      _Float16 wh = (_Float16)w;
      half2v ww = {wh, wh};
#pragma unroll
      for (int j = 0; j < 4; j++) ha[j]      += t0.h[j] * ww;
#pragma unroll
      for (int j = 0; j < 4; j++) ha[4 + j]  += t1.h[j] * ww;
#pragma unroll
      for (int j = 0; j < 4; j++) ha[8 + j]  += t2.h[j] * ww;
#pragma unroll
      for (int j = 0; j < 4; j++) ha[12 + j] += t3.h[j] * ww;
      ha[16] += t4.h[0] * ww;
      ha[17] += t4.h[1] * ww;
    }
  }
  float inv = 1.f / fmaxf(dsum, 1e-7f);
  outImg[((size_t)(b * 6 + dir * 3 + 0)) * HW0 + q] = (float)ha[0][0] * inv;
  outImg[((size_t)(b * 6 + dir * 3 + 1)) * HW0 + q] = (float)ha[0][1] * inv;
  outImg[((size_t)(b * 6 + dir * 3 + 2)) * HW0 + q] = (float)ha[1][0] * inv;
  outSig[((size_t)(b * 2 + dir)) * HW0 + q]         = (float)ha[1][1] * inv;
#pragma unroll
  for (int j = 0; j < 16; j++) {
    outFeat[((size_t)(b * 64 + dir * 32 + 2 * j + 0)) * HW0 + q] = (float)ha[2 + j][0] * inv;
    outFeat[((size_t)(b * 64 + dir * 32 + 2 * j + 1)) * HW0 + q] = (float)ha[2 + j][1] * inv;
  }
}

template <int C, int Hd, int Wd, int RS, int Z>
__device__ __forceinline__ void gather_feat_body(
    const float* __restrict__ recs, const uint2* __restrict__ cs,
    float* __restrict__ outF, int lb) {
  constexpr int HWd = Hd * Wd;
  constexpr int NCX = Wd + 1;
  constexpr int NC  = (Wd + 1) * (Hd + 1);
  constexpr int GX = HWd / 256;
  // natural order (see gather_full_body)
  int q = (lb % GX) * 256 + (int)threadIdx.x;
  int b = (lb / GX) % B;
  int dz = lb / (GX * B);
  int z = dz % Z, dir = dz / Z;
  int c0 = z * 32;
  int nb = dir * B + b;
  int qx = q % Wd, qy = q / Wd;
  half2v ha[16];
#pragma unroll
  for (int j = 0; j < 16; j++) ha[j] = half2v{(_Float16)0.f, (_Float16)0.f};
  float dsum = 0.f;
  for (int ky = 0; ky < 2; ky++) {
    int cy = qy - 1 + ky;
    int base = nb * NC + (cy + 1) * NCX + qx;
    uint2 scL = cs[base];
    uint2 scR = cs[base + 1];
    unsigned s0 = scL.x, sb = scR.x, sE = scR.x + scR.y;
    for (unsigned s = s0; s < sE; s++) {
      const float* rp = recs + (size_t)s * RS;
      const floatx4* r4 = (const floatx4*)rp;
      union { floatx4 f; half2v h[4]; } t0, t1, t2, t3;
      t0.f = r4[4 * z + 0]; t1.f = r4[4 * z + 1];
      t2.f = r4[4 * z + 2]; t3.f = r4[4 * z + 3];
      float2 hd = *(const float2*)(rp + C / 2);
      float wx = (s < sb) ? hd.x : (1.f - hd.x);
      float wy = ky ? (1.f - hd.y) : hd.y;
      float w = wx * wy;
      dsum += w;
      _Float16 wh = (_Float16)w;
      half2v ww = {wh, wh};
#pragma unroll
      for (int j = 0; j < 4; j++) ha[j]      += t0.h[j] * ww;
#pragma unroll
      for (int j = 0; j < 4; j++) ha[4 + j]  += t1.h[j] * ww;
#pragma unroll
      for (int j = 0; j < 4; j++) ha[8 + j]  += t2.h[j] * ww;
#pragma unroll
      for (int j = 0; j < 4; j++) ha[12 + j] += t3.h[j] * ww;
    }
  }
  float inv = 1.f / fmaxf(dsum, 1e-7f);
  size_t obase = ((size_t)(b * 2 * C + dir * C + c0)) * HWd + q;
#pragma unroll
  for (int j = 0; j < 16; j++) {
    outF[obase + (size_t)(2 * j + 0) * HWd] = (float)ha[j][0] * inv;
    outF[obase + (size_t)(2 * j + 1) * HWd] = (float)ha[j][1] * inv;
  }
}

// ================= merged kernels =================

__global__ __launch_bounds__(256) void k_front(
    const float* f01, const float* s01, const float* f10, const float* s10,
    float* flowF, unsigned* cntF,
    const float* img0, const float* img1, float* msum,
    const float* w2, const float* w3, const float* w4, const float* w5, const float* w6,
    _Float16* o2, _Float16* o3, _Float16* o4, _Float16* o5, _Float16* o6) {
  int f = blockIdx.x;
  if (f < NB_IF) d_interflow2(f01, s01, f10, s10, flowF, cntF, f);
  else if (f < NB_IF + NB_MEAN) d_mean(img0, img1, msum, f - NB_IF);
  else d_wtrans(w2, w3, w4, w5, w6, o2, o3, o4, o5, o6, f - NB_IF - NB_MEAN);
}

__global__ __launch_bounds__(256) void k_down_conv1(
    const float* flowF, float* flowH, unsigned* cntH, float* flowQ, unsigned* cntQ,
    const float* img0, const float* img1, const float* msum, float invCnt,
    const float* w1, const float* b1, const float* a1, _Float16* Ah) {
  int f = blockIdx.x;
  if (f < NB_DH) d_downflow2<2, H1, W1>(flowF, flowH, cntH, f);
  else if (f < NB_DH + NB_DQ) d_downflow2<4, H2, W2>(flowF, flowQ, cntQ, f - NB_DH);
  else d_conv1(img0, img1, msum, invCnt, w1, b1, a1, Ah, f - NB_DH - NB_DQ);
}

__global__ __launch_bounds__(256) void k_scan_conv2(
    const unsigned* cntAll, unsigned* tpre, unsigned* psum,
    const _Float16* Ah, const _Float16* wt2, const float* b2, const float* a2,
    _Float16* Bh) {
  int f = blockIdx.x;
  if (f < NCHUNKS) d_scan_part(cntAll, tpre, psum, f);
  else conv_mfma_body<32, 32, 1, 8>(Ah, wt2, b2, a2, Bh, H0, W0, H0, W0,
                                    224, 1, 8, f - NCHUNKS);
}

__global__ __launch_bounds__(256) void k_scan_apply(
    const unsigned* __restrict__ cnt, const unsigned* __restrict__ tpre,
    const unsigned* __restrict__ psum,
    uint2* __restrict__ cs, unsigned* __restrict__ curs) {
  int b = blockIdx.x, t = threadIdx.x;
  int off, sz, ci;
  chunk_map(b, off, sz, ci);
  __shared__ unsigned cbs;
  if (t == 0) {
    int first = (off == 0) ? 0 : (off == SZ_F ? NCH_F : NCH_F + NCH_H);
    unsigned c = 0;
    for (int k = first; k < first + ci; k++) c += psum[k];
    cbs = c;
  }
  __syncthreads();
  int base = off + ci * CHUNK + t * 64;
  int lim = off + min(sz, (ci + 1) * CHUNK);
  unsigned run = cbs + tpre[b * 256 + t];
  for (int j = 0; j < 64; j++) {
    int idx = base + j;
    if (idx < lim) {
      unsigned c = cnt[idx];
      cs[idx] = make_uint2(run, c);
      curs[idx] = run;
      run += c;
    }
  }
}

__global__ __launch_bounds__(256) void k_packF_conv3(
    const float* img0, const float* img1, const float* msum, float invCnt,
    const _Float16* Bh, const float* s01, const float* s10, const float* flowF,
    float* recs, unsigned* cursF,
    const _Float16* wt3, const float* b3, const float* a3, _Float16* Ah) {
  int f = blockIdx.x;
  if (f < NB_PF)
    pack_full_body(img0, img1, msum, invCnt, Bh, s01, s10, flowF, recs, cursF, f);
  else
    conv_mfma_body<32, 64, 2, 4>(Bh, wt3, b3, a3, Ah, H0, W0, H1, W1,
                                 112, 2, 8, f - NB_PF);
}

__global__ __launch_bounds__(256) void k_gatherF_conv4(
    const float* recs, const uint2* csF,
    float* outImg, float* outFeat, float* outSig,
    const _Float16* Ah, const _Float16* wt4, const float* b4, const float* a4,
    _Float16* Bh) {
  int f = blockIdx.x;
  if (f < NB_GF)
    gather_full_body(recs, csF, outImg, outFeat, outSig, f);
  else
    conv_mfma_body<64, 64, 1, 8>(Ah, wt4, b4, a4, Bh, H1, W1, H1, W1,
                                 56, 2, 8, f - NB_GF);
}

__global__ __launch_bounds__(256) void k_packH_conv5(
    const _Float16* Bh, const float* flowH, float* recs, unsigned* cursH,
    const _Float16* wt5, const float* b5, const float* a5, _Float16* Ah) {
  int f = blockIdx.x;
  if (f < NB_PH)
    pack_feat_body<64, H1, W1, RS_H>(Bh, flowH, recs, cursH, f);
  else
    conv_mfma_body<64, 96, 2, 4>(Bh, wt5, b5, a5, Ah, H1, W1, H2, W2,
                                 28, 3, 8, f - NB_PH);
}

__global__ __launch_bounds__(256) void k_gatherH_conv6(
    const float* recs, const uint2* csH, float* outF2,
    const _Float16* Ah, const _Float16* wt6, const float* b6, const float* a6,
    _Float16* Bh) {
  int f = blockIdx.x;
  if (f < NB_GH)
    gather_feat_body<64, H1, W1, RS_H, 2>(recs, csH, outF2, f);
  else
    conv_mfma_body<96, 96, 1, 4>(Ah, wt6, b6, a6, Bh, H2, W2, H2, W2,
                                 28, 3, 8, f - NB_GH);
}

__global__ __launch_bounds__(256) void k_packQ(
    const _Float16* Bh, const float* flowQ, float* recs, unsigned* cursQ) {
  pack_feat_body<96, H2, W2, RS_Q>(Bh, flowQ, recs, cursQ, blockIdx.x);
}

__global__ __launch_bounds__(256) void k_gatherQ(
    const float* recs, const uint2* csQ, float* outF3) {
  gather_feat_body<96, H2, W2, RS_Q, 3>(recs, csQ, outF3, blockIdx.x);
}

extern "C" void kernel_launch(void* const* d_in, const int* in_sizes, int n_in,
                              void* d_out, int out_size, void* d_ws, size_t ws_size,
                              hipStream_t stream) {
  (void)in_sizes; (void)n_in; (void)out_size;
  if (ws_size < WS_FLOATS * sizeof(float)) return;

  const float* img0    = (const float*)d_in[0];
  const float* img1    = (const float*)d_in[1];
  const float* flow01  = (const float*)d_in[2];
  const float* sigma01 = (const float*)d_in[3];
  const float* flow10  = (const float*)d_in[4];
  const float* sigma10 = (const float*)d_in[5];
  const float* wp[6]; const float* bp[6]; const float* ap[6];
  for (int i = 0; i < 6; i++) {
    wp[i] = (const float*)(d_in[6 + 3 * i]);
    bp[i] = (const float*)(d_in[7 + 3 * i]);
    ap[i] = (const float*)(d_in[8 + 3 * i]);
  }
  float* ws  = (float*)d_ws;
  float* out = (float*)d_out;

  unsigned* cntAll  = (unsigned*)(ws + OFF_CNT);
  unsigned* cntF = cntAll;
  unsigned* cntH = cntAll + SZ_F;
  unsigned* cntQ = cntAll + SZ_F + SZ_H;
  uint2*    csAll = (uint2*)(ws + OFF_CS);
  uint2*    csF = csAll, *csH = csAll + SZ_F, *csQ = csAll + SZ_F + SZ_H;
  unsigned* cursAll  = (unsigned*)(ws + OFF_CURS);
  unsigned* cursF = cursAll, *cursH = cursAll + SZ_F, *cursQ = cursAll + SZ_F + SZ_H;
  unsigned* tpre  = (unsigned*)(ws + OFF_TPRE);
  unsigned* psum  = (unsigned*)(ws + OFF_PSUM);
  float*    recs  = ws + OFF_RECS;
  _Float16* Ah = (_Float16*)(ws + OFF_BUFA);
  _Float16* Bh = (_Float16*)(ws + OFF_BUFB);
  _Float16* wt[5] = {(_Float16*)(ws + OFF_WT2), (_Float16*)(ws + OFF_WT3),
                     (_Float16*)(ws + OFF_WT4), (_Float16*)(ws + OFF_WT5),
                     (_Float16*)(ws + OFF_WT6)};
  float* flowF = ws + OFF_FLOW;
  float* flowH = ws + OFF_FLH;
  float* flowQ = ws + OFF_FLQ;

  const float invCnt = 1.f / (6.f * (float)HW0);

  dim3 blk(256);

  // 0: fast zero of mean + cnt regions
  k_zero<<<dim3(1024), blk, 0, stream>>>((floatx4*)ws, (int)(ZERO_FLOATS / 4));

  // 1: interflow || mean || wtrans
  k_front<<<dim3(NB_IF + NB_MEAN + NB_WT), blk, 0, stream>>>(
      flow01, sigma01, flow10, sigma10, flowF, cntF,
      img0, img1, ws + OFF_MEAN,
      wp[1], wp[2], wp[3], wp[4], wp[5], wt[0], wt[1], wt[2], wt[3], wt[4]);

  // 2: downflowH || downflowQ || conv1
  k_down_conv1<<<dim3(NB_DH + NB_DQ + NB_C1), blk, 0, stream>>>(
      flowF, flowH, cntH, flowQ, cntQ,
      img0, img1, ws + OFF_MEAN, invCnt, wp[0], bp[0], ap[0], Ah);

  // 3: scan_part || conv2
  k_scan_conv2<<<dim3(NCHUNKS + NB_C2), blk, 0, stream>>>(
      cntAll, tpre, psum, Ah, wt[0], bp[1], ap[1], Bh);

  // 4: scan_apply
  k_scan_apply<<<dim3(NCHUNKS), blk, 0, stream>>>(cntAll, tpre, psum, csAll, cursAll);

  // 5: pack_full || conv3
  k_packF_conv3<<<dim3(NB_PF + NB_C3), blk, 0, stream>>>(
      img0, img1, ws + OFF_MEAN, invCnt, Bh, sigma01, sigma10, flowF,
      recs, cursF, wt[1], bp[2], ap[2], Ah);

  // 6: gather_full || conv4
  k_gatherF_conv4<<<dim3(NB_GF + NB_C4), blk, 0, stream>>>(
      recs, csF, out + O_IMG, out + O_F1, out + O_SIG,
      Ah, wt[2], bp[3], ap[3], Bh);

  // 7: pack_H || conv5
  k_packH_conv5<<<dim3(NB_PH + NB_C5), blk, 0, stream>>>(
      Bh, flowH, recs, cursH, wt[3], bp[4], ap[4], Ah);

  // 8: gather_H || conv6
  k_gatherH_conv6<<<dim3(NB_GH + NB_C6), blk, 0, stream>>>(
      recs, csH, out + O_F2, Ah, wt[4], bp[5], ap[5], Bh);

  // 9: pack_Q ; 10: gather_Q
  k_packQ<<<dim3((HW2 / 256) * B * 2), blk, 0, stream>>>(Bh, flowQ, recs, cursQ);
  k_gatherQ<<<dim3((HW2 / 256) * B * 6), blk, 0, stream>>>(recs, csQ, out + O_F3);
}